// Round 14
// baseline (325.454 us; speedup 1.0000x reference)
//
#include <hip/hip_runtime.h>
#include <hip/hip_fp16.h>

#define NN 100000
#define NEG_SLOPE 0.2f
#define FOUT 32
#define BKT 128                       // dst-nodes per bucket
#define NBK ((NN + BKT - 1) / BKT)    // 782
#define CHUNK 4096

__device__ __forceinline__ float lrelu(float e) { return e > 0.f ? e : NEG_SLOPE * e; }

// fp16x4 load via 32-bit byte offset -> float4 (SGPR base + 32b voffset form)
__device__ __forceinline__ float4 ldH4o(const __half* __restrict__ H, unsigned off) {
    uint2 u = *(const uint2*)((const char*)H + off);
    float2 f01 = __half22float2(*reinterpret_cast<const __half2*>(&u.x));
    float2 f23 = __half22float2(*reinterpret_cast<const __half2*>(&u.y));
    return make_float4(f01.x, f01.y, f23.x, f23.y);
}

// ---------------- node transform (standalone; tier-2/3): h = X@W (+bias), att dots --------
template <bool ATT, bool ADD_BIAS, typename TO>
__global__ void transform_kernel(const float* __restrict__ X, const float* __restrict__ W,
                                 const float* __restrict__ att_s, const float* __restrict__ att_d,
                                 const float* __restrict__ bias,
                                 TO* __restrict__ H, float* __restrict__ a_src,
                                 float* __restrict__ a_dst, int N, int Fin) {
    __shared__ float Wl[128 * FOUT];
    __shared__ float Xl[8 * 128];
    const int t = threadIdx.x;
    const int nodeBase = blockIdx.x * 8;
    const int vprW = Fin * FOUT / 4;
    for (int i = t; i < vprW; i += 256) ((float4*)Wl)[i] = ((const float4*)W)[i];
    const int vpr = Fin / 4;
    for (int i = t; i < 8 * vpr; i += 256) {
        int r = i / vpr, c = i - r * vpr;
        int n = nodeBase + r;
        ((float4*)Xl)[i] = (n < N) ? ((const float4*)X)[(size_t)n * vpr + c]
                                   : make_float4(0.f, 0.f, 0.f, 0.f);
    }
    __syncthreads();
    const int ln = t >> 5;
    const int j  = t & 31;
    const int n  = nodeBase + ln;
    float acc = 0.f;
    for (int k = 0; k < Fin; ++k)
        acc = fmaf(Xl[ln * Fin + k], Wl[k * FOUT + j], acc);
    if (ADD_BIAS) acc += bias[j];
    if (n < N) H[(size_t)n * FOUT + j] = (TO)acc;
    if (ATT) {
        float vs = acc * att_s[j];
        float vd = acc * att_d[j];
        #pragma unroll
        for (int m = 16; m >= 1; m >>= 1) {
            vs += __shfl_xor(vs, m, 32);
            vd += __shfl_xor(vd, m, 32);
        }
        if (j == 0 && n < N) { a_src[n] = vs; a_dst[n] = vd; }
    }
}

// ---------------- fused: bucket_count (blocks < cb) + transform1 (blocks >= cb) -----------
__global__ __launch_bounds__(256)
void count_tr1_kernel(const int* __restrict__ dst, int E, int cb, int* __restrict__ bktcnt,
                      const float* __restrict__ X, const float* __restrict__ W,
                      const float* __restrict__ att_s, const float* __restrict__ att_d,
                      __half* __restrict__ H, float* __restrict__ a_src,
                      float* __restrict__ a_dst, int N, int Fin) {
    __shared__ float Wl[128 * FOUT];
    __shared__ float Xl[8 * 128];
    const int t = threadIdx.x;
    if ((int)blockIdx.x < cb) {
        int* hist = (int*)Wl;
        const int e0 = blockIdx.x * CHUNK;
        const int e1 = min(e0 + CHUNK, E);
        for (int i = t; i < NBK; i += 256) hist[i] = 0;
        __syncthreads();
        for (int i = e0 + t; i < e1; i += 256)
            atomicAdd(&hist[((unsigned)dst[i]) / BKT], 1);
        __syncthreads();
        for (int i = t; i < NBK; i += 256) {
            int h = hist[i];
            if (h) atomicAdd(&bktcnt[i], h);
        }
        return;
    }
    const int nodeBase = ((int)blockIdx.x - cb) * 8;
    const int vprW = Fin * FOUT / 4;
    for (int i = t; i < vprW; i += 256) ((float4*)Wl)[i] = ((const float4*)W)[i];
    const int vpr = Fin / 4;
    for (int i = t; i < 8 * vpr; i += 256) {
        int r = i / vpr, c = i - r * vpr;
        int n = nodeBase + r;
        ((float4*)Xl)[i] = (n < N) ? ((const float4*)X)[(size_t)n * vpr + c]
                                   : make_float4(0.f, 0.f, 0.f, 0.f);
    }
    __syncthreads();
    const int ln = t >> 5;
    const int j  = t & 31;
    const int n  = nodeBase + ln;
    float acc = 0.f;
    for (int k = 0; k < Fin; ++k)
        acc = fmaf(Xl[ln * Fin + k], Wl[k * FOUT + j], acc);
    if (n < N) H[(size_t)n * FOUT + j] = (__half)acc;
    float vs = acc * att_s[j];
    float vd = acc * att_d[j];
    #pragma unroll
    for (int m = 16; m >= 1; m >>= 1) {
        vs += __shfl_xor(vs, m, 32);
        vd += __shfl_xor(vd, m, 32);
    }
    if (j == 0 && n < N) { a_src[n] = vs; a_dst[n] = vd; }
}

// generic scan; optionally writes a second copy of the result (cursor init)
template <int BS>
__global__ void scan_blocks_kernel(const int* __restrict__ in, int n,
                                   int* __restrict__ out, int* __restrict__ out2,
                                   int* __restrict__ bsums) {
    int g = blockIdx.x * BS + threadIdx.x;
    int v = (g < n) ? in[g] : 0;
    int lane = threadIdx.x & 63;
    int w = threadIdx.x >> 6;
    int x = v;
    #pragma unroll
    for (int o = 1; o < 64; o <<= 1) {
        int y = __shfl_up(x, o, 64);
        if (lane >= o) x += y;
    }
    __shared__ int ws[BS / 64];
    if (lane == 63) ws[w] = x;
    __syncthreads();
    if (threadIdx.x == 0) {
        int a = 0;
        for (int k = 0; k < BS / 64; ++k) { int tv = ws[k]; ws[k] = a; a += tv; }
        if (bsums) bsums[blockIdx.x] = a;
    }
    __syncthreads();
    int ex = x - v + ws[w];
    if (g < n) {
        out[g] = ex;
        if (out2) out2[g] = ex;
    }
}

__global__ void add_offsets_kernel(int* __restrict__ out, const int* __restrict__ bsums, int n) {
    int g = blockIdx.x * 256 + threadIdx.x;
    if (g < n) out[g] += bsums[blockIdx.x];
}

__global__ void copy_kernel(const int* __restrict__ in, int* __restrict__ out, int n) {
    int i = blockIdx.x * blockDim.x + threadIdx.x;
    if (i < n) out[i] = in[i];
}

// pass 1: bin edges by dst bucket, packed (d_local<<17 | s), contiguous runs per (block,bucket)
__global__ __launch_bounds__(256)
void partition_kernel(const int* __restrict__ src, const int* __restrict__ dst, int E,
                      int* __restrict__ bcur, unsigned* __restrict__ pbuf) {
    __shared__ int hist[NBK];
    __shared__ int runbase[NBK];
    __shared__ int c2[NBK];
    const int tid = threadIdx.x;
    const int e0 = blockIdx.x * CHUNK;
    const int e1 = min(e0 + CHUNK, E);
    for (int t = tid; t < NBK; t += 256) { hist[t] = 0; c2[t] = 0; }
    __syncthreads();
    for (int i = e0 + tid; i < e1; i += 256)
        atomicAdd(&hist[((unsigned)dst[i]) / BKT], 1);
    __syncthreads();
    for (int t = tid; t < NBK; t += 256) {
        int h = hist[t];
        runbase[t] = h ? atomicAdd(&bcur[t], h) : 0;
    }
    __syncthreads();
    for (int i = e0 + tid; i < e1; i += 256) {
        int d = dst[i], s = src[i];
        int b = ((unsigned)d) / BKT;
        int ofs = atomicAdd(&c2[b], 1);
        pbuf[runbase[b] + ofs] = (((unsigned)(d & (BKT - 1))) << 17) | (unsigned)s;
    }
}

// pass 2: one block per bucket. Local per-node counts (LDS atomics) + LDS scan
// -> writes ptr AND ssrc (self-loop at slot 0); scatter confined to the bucket window.
__global__ __launch_bounds__(256)
void bucket_scatter_kernel(const int* __restrict__ bktbase, const unsigned* __restrict__ pbuf,
                           int E, int* __restrict__ ptr, int* __restrict__ ssrc) {
    __shared__ int lcnt[BKT];
    __shared__ int cur[BKT];
    __shared__ int wsum[4];
    const int b = blockIdx.x;
    const int tid = threadIdx.x;
    const int n0 = b * BKT;
    const int nodes = min(BKT, NN - n0);
    const int bstart = bktbase[b];
    const int bend = (b == NBK - 1) ? E : bktbase[b + 1];
    if (tid < BKT) lcnt[tid] = 0;
    __syncthreads();
    for (int i = bstart + tid; i < bend; i += 256)
        atomicAdd(&lcnt[pbuf[i] >> 17], 1);
    __syncthreads();
    int v = (tid < nodes) ? (lcnt[tid] + 1) : 0;
    int lane = tid & 63, w = tid >> 6;
    int x = v;
    #pragma unroll
    for (int o = 1; o < 64; o <<= 1) {
        int y = __shfl_up(x, o, 64);
        if (lane >= o) x += y;
    }
    if (lane == 63) wsum[w] = x;
    __syncthreads();
    if (tid == 0) {
        int a = 0;
        #pragma unroll
        for (int k = 0; k < 4; ++k) { int t2 = wsum[k]; wsum[k] = a; a += t2; }
    }
    __syncthreads();
    int ex = x - v + wsum[w];
    if (tid < nodes) {
        int p = bstart + n0 + ex;
        ptr[n0 + tid] = p;
        ssrc[p] = n0 + tid;             // self loop at slot 0
        cur[tid] = p + 1;
    }
    __syncthreads();
    for (int i = bstart + tid; i < bend; i += 256) {
        unsigned u = pbuf[i];
        int pos = atomicAdd(&cur[u >> 17], 1);
        ssrc[pos] = (int)(u & 0x1FFFFu);
    }
}

// ---------------- tier-2 helpers ----------------
__global__ void init_one_kernel(int* __restrict__ cnt, int n) {
    int i = blockIdx.x * blockDim.x + threadIdx.x;
    if (i < n) cnt[i] = 1;
}
__global__ void hist_kernel(const int* __restrict__ dst, int E, int* __restrict__ cnt) {
    int i = blockIdx.x * blockDim.x + threadIdx.x;
    if (i < E) atomicAdd(&cnt[dst[i]], 1);
}
__global__ void scatter_kernel(const int* __restrict__ src, const int* __restrict__ dst,
                               int E, int ET, int* __restrict__ cfill, int* __restrict__ ssrc) {
    int i = blockIdx.x * blockDim.x + threadIdx.x;
    if (i >= ET) return;
    int s, d;
    if (i < E) { s = src[i]; d = dst[i]; }
    else       { s = d = i - E; }
    int pos = atomicAdd(&cfill[d], 1);
    ssrc[pos] = s;
}

// ---------------- fused per-node GAT aggregation + projection (single-pass CSR gather) -----
// one 64-lane wave per node; eighth o handles edges k === o (mod 8), lane t holds
// features 4t..4t+3. Single traversal (shift-invariant softmax; |e|<~20). H fp16
// (64B rows = 1 line/gather). 32-BIT byte-offset addressing (all tables < 16MB) ->
// SGPR-base + 32b voffset loads, no 64-bit index math in the hot loop.
// Epilogue: full-wave 32x32 projection (validated r13).
//   MODE 0 (MID):  outh = v@W2 (fp16); att dots -> oasrc/oadst
//   MODE 1 (LAST): outf = v@Wr + br (fp32 readout)
template <int MODE>
__global__ __launch_bounds__(256)
void gat_csr_kernel(const int* __restrict__ ptr, const int* __restrict__ ssrc,
                    const float* __restrict__ asrc, const float* __restrict__ adst,
                    const __half* __restrict__ H, const float* __restrict__ bias,
                    const float* __restrict__ Wp, const float* __restrict__ bp,
                    const float* __restrict__ att_s, const float* __restrict__ att_d,
                    __half* __restrict__ outh, float* __restrict__ outf,
                    float* __restrict__ oasrc, float* __restrict__ oadst, int ET) {
    __shared__ float Wl[32 * 32];
    __shared__ float hbuf[4][FOUT];
    const int tid = threadIdx.x;
    for (int i = tid; i < 1024; i += 256) Wl[i] = Wp[i];
    const int w = tid >> 6, lane = tid & 63;
    const int wid = blockIdx.x * 4 + w;
    const int beg = ptr[wid];
    const int end = (wid == NN - 1) ? ET : ptr[wid + 1];
    const int deg = end - beg;
    const float ad = adst[wid];
    const int o = lane >> 3, t = lane & 7;
    const unsigned tb = (unsigned)(t << 3);     // byte offset of feature quad in a 64B row
    const char* Sb = (const char*)(ssrc + beg); // per-node edge list base
    const char* Ab = (const char*)asrc;

    float4 a0 = make_float4(0.f, 0.f, 0.f, 0.f);
    float4 a1 = make_float4(0.f, 0.f, 0.f, 0.f);
    float4 a2 = make_float4(0.f, 0.f, 0.f, 0.f);
    float4 a3 = make_float4(0.f, 0.f, 0.f, 0.f);
    float sm0 = 0.f, sm1 = 0.f;
    int k = o;
    for (; k + 24 < deg; k += 32) {
        unsigned kb = (unsigned)k << 2;
        int s0 = *(const int*)(Sb + kb);
        int s1 = *(const int*)(Sb + kb + 32);
        int s2 = *(const int*)(Sb + kb + 64);
        int s3 = *(const int*)(Sb + kb + 96);
        float e0 = *(const float*)(Ab + ((unsigned)s0 << 2));
        float e1 = *(const float*)(Ab + ((unsigned)s1 << 2));
        float e2 = *(const float*)(Ab + ((unsigned)s2 << 2));
        float e3 = *(const float*)(Ab + ((unsigned)s3 << 2));
        float4 h0 = ldH4o(H, ((unsigned)s0 << 6) + tb);
        float4 h1 = ldH4o(H, ((unsigned)s1 << 6) + tb);
        float4 h2 = ldH4o(H, ((unsigned)s2 << 6) + tb);
        float4 h3 = ldH4o(H, ((unsigned)s3 << 6) + tb);
        float p0 = __expf(lrelu(e0 + ad));
        float p1 = __expf(lrelu(e1 + ad));
        float p2 = __expf(lrelu(e2 + ad));
        float p3 = __expf(lrelu(e3 + ad));
        sm0 += p0 + p2; sm1 += p1 + p3;
        a0.x = fmaf(p0, h0.x, a0.x); a0.y = fmaf(p0, h0.y, a0.y);
        a0.z = fmaf(p0, h0.z, a0.z); a0.w = fmaf(p0, h0.w, a0.w);
        a1.x = fmaf(p1, h1.x, a1.x); a1.y = fmaf(p1, h1.y, a1.y);
        a1.z = fmaf(p1, h1.z, a1.z); a1.w = fmaf(p1, h1.w, a1.w);
        a2.x = fmaf(p2, h2.x, a2.x); a2.y = fmaf(p2, h2.y, a2.y);
        a2.z = fmaf(p2, h2.z, a2.z); a2.w = fmaf(p2, h2.w, a2.w);
        a3.x = fmaf(p3, h3.x, a3.x); a3.y = fmaf(p3, h3.y, a3.y);
        a3.z = fmaf(p3, h3.z, a3.z); a3.w = fmaf(p3, h3.w, a3.w);
    }
    for (; k < deg; k += 8) {
        int s = *(const int*)(Sb + ((unsigned)k << 2));
        float e = *(const float*)(Ab + ((unsigned)s << 2));
        float4 h = ldH4o(H, ((unsigned)s << 6) + tb);
        float p = __expf(lrelu(e + ad));
        sm0 += p;
        a0.x = fmaf(p, h.x, a0.x); a0.y = fmaf(p, h.y, a0.y);
        a0.z = fmaf(p, h.z, a0.z); a0.w = fmaf(p, h.w, a0.w);
    }
    float4 a = make_float4(a0.x + a1.x + a2.x + a3.x, a0.y + a1.y + a2.y + a3.y,
                           a0.z + a1.z + a2.z + a3.z, a0.w + a1.w + a2.w + a3.w);
    float sm = sm0 + sm1;
    #pragma unroll
    for (int off = 8; off <= 32; off <<= 1) {
        a.x += __shfl_xor(a.x, off, 64);
        a.y += __shfl_xor(a.y, off, 64);
        a.z += __shfl_xor(a.z, off, 64);
        a.w += __shfl_xor(a.w, off, 64);
        sm  += __shfl_xor(sm,  off, 64);
    }
    const float inv = 1.f / (sm + 1e-16f);

    // v = relu(agg*inv + bias) -> hbuf (8 lanes), then full-wave projection
    if (lane < 8) {
        float4 bv = *(const float4*)(bias + 4 * t);
        hbuf[w][4 * t]     = fmaxf(fmaf(a.x, inv, bv.x), 0.f);
        hbuf[w][4 * t + 1] = fmaxf(fmaf(a.y, inv, bv.y), 0.f);
        hbuf[w][4 * t + 2] = fmaxf(fmaf(a.z, inv, bv.z), 0.f);
        hbuf[w][4 * t + 3] = fmaxf(fmaf(a.w, inv, bv.w), 0.f);
    }
    __syncthreads();                 // Wl + hbuf visible (uniform barrier)
    {
        const int j = lane & 31, hh = lane >> 5;
        float r = 0.f;
        #pragma unroll
        for (int kk = 0; kk < 16; ++kk) {
            int k2 = hh * 16 + kk;
            r = fmaf(hbuf[w][k2], Wl[k2 * 32 + j], r);
        }
        r += __shfl_xor(r, 32, 64);
        if (MODE == 1) {
            if (lane < 32) outf[(size_t)wid * FOUT + j] = r + bp[j];
        } else {
            float rn = __shfl_xor(r, 1, 64);
            if (lane < 32 && !(j & 1)) {
                __half2 h2 = __float22half2_rn(make_float2(r, rn));
                *(__half2*)(outh + (size_t)wid * FOUT + j) = h2;
            }
            float vs = r * att_s[j];
            float vd = r * att_d[j];
            #pragma unroll
            for (int off = 1; off < 32; off <<= 1) {
                vs += __shfl_xor(vs, off, 64);
                vd += __shfl_xor(vd, off, 64);
            }
            if (lane == 0) { oasrc[wid] = vs; oadst[wid] = vd; }
        }
    }
}

// ---------------- tier-3 fallback (round-2 proven atomic path, all fp32) ----------------
__device__ __forceinline__ unsigned ordf(float f) {
    unsigned u = __float_as_uint(f);
    return (u & 0x80000000u) ? ~u : (u | 0x80000000u);
}
__device__ __forceinline__ float unordf(unsigned u) {
    return (u & 0x80000000u) ? __uint_as_float(u & 0x7FFFFFFFu) : __uint_as_float(~u);
}
__device__ __forceinline__ void edge_sd(int i, int E, const int* __restrict__ src,
                                        const int* __restrict__ dst, int& s, int& d) {
    if (i < E) { s = src[i]; d = dst[i]; }
    else       { s = d = i - E; }
}
__global__ void edge_max_kernel(const int* __restrict__ src, const int* __restrict__ dst,
                                const float* __restrict__ a_src, const float* __restrict__ a_dst,
                                unsigned* __restrict__ m, int E, int ET) {
    int i = blockIdx.x * blockDim.x + threadIdx.x;
    if (i >= ET) return;
    int s, d; edge_sd(i, E, src, dst, s, d);
    atomicMax(m + d, ordf(lrelu(a_src[s] + a_dst[d])));
}
__global__ void edge_denom_kernel(const int* __restrict__ src, const int* __restrict__ dst,
                                  const float* __restrict__ a_src, const float* __restrict__ a_dst,
                                  const unsigned* __restrict__ m, float* __restrict__ denom,
                                  int E, int ET) {
    int i = blockIdx.x * blockDim.x + threadIdx.x;
    if (i >= ET) return;
    int s, d; edge_sd(i, E, src, dst, s, d);
    atomicAdd(denom + d, __expf(lrelu(a_src[s] + a_dst[d]) - unordf(m[d])));
}
__global__ void edge_accum_kernel(const int* __restrict__ src, const int* __restrict__ dst,
                                  const float* __restrict__ a_src, const float* __restrict__ a_dst,
                                  const unsigned* __restrict__ m, const float* __restrict__ denom,
                                  const float* __restrict__ H, float* __restrict__ accum,
                                  int E, int ET) {
    long tid = (long)blockIdx.x * blockDim.x + threadIdx.x;
    if (tid >= (long)ET * FOUT) return;
    int i = (int)(tid >> 5);
    int j = (int)(tid & 31);
    int s, d; edge_sd(i, E, src, dst, s, d);
    float w = __expf(lrelu(a_src[s] + a_dst[d]) - unordf(m[d])) / (denom[d] + 1e-16f);
    atomicAdd(accum + (long)d * FOUT + j, w * H[(long)s * FOUT + j]);
}
__global__ void finalize_kernel(float* __restrict__ accum, const float* __restrict__ bias, int N) {
    int tid = blockIdx.x * blockDim.x + threadIdx.x;
    if (tid >= N * FOUT) return;
    int j = tid & 31;
    accum[tid] = fmaxf(accum[tid] + bias[j], 0.f);
}

extern "C" void kernel_launch(void* const* d_in, const int* in_sizes, int n_in,
                              void* d_out, int out_size, void* d_ws, size_t ws_size,
                              hipStream_t stream) {
    const float* x   = (const float*)d_in[0];
    const int*   ei  = (const int*)d_in[1];
    const float* W1  = (const float*)d_in[2];
    const float* as1 = (const float*)d_in[3];
    const float* ad1 = (const float*)d_in[4];
    const float* b1  = (const float*)d_in[5];
    const float* W2  = (const float*)d_in[6];
    const float* as2 = (const float*)d_in[7];
    const float* ad2 = (const float*)d_in[8];
    const float* b2  = (const float*)d_in[9];
    const float* Wr  = (const float*)d_in[10];
    const float* br  = (const float*)d_in[11];
    float* out = (float*)d_out;

    const int E  = in_sizes[1] / 2;
    const int*  src = ei;
    const int*  dst = ei + E;
    const int ET = E + NN;

    const size_t NF = (size_t)NN * FOUT;
    // layout (float units): A(NF) | H(NF) | asrc(NN) | adst(NN) | asrc2(NN) | adst2(NN)
    //                       | ptr(NN) | cnt(NN) | bsum(512) | ssrc(ET)
    float* A     = (float*)d_ws;
    float* H     = A + NF;
    float* asrc  = H + NF;
    float* adst  = asrc + NN;
    float* asrc2 = adst + NN;
    float* adst2 = asrc2 + NN;
    int*   ptr   = (int*)(adst2 + NN);
    int*   cnt   = ptr + NN;
    int*   bsum  = cnt + NN;
    int*   ssrc  = bsum + 512;
    __half* H1h  = (__half*)H;
    __half* H2h  = (__half*)A;
    const size_t need = (2 * NF + 6 * (size_t)NN + 512 + (size_t)ET) * 4;

    dim3 blk(256);
    const int nb  = (NN + 7) / 8;
    const int fb  = (NN * FOUT + 255) / 256;
    const int nb1 = (NN + 255) / 256;   // 391

    if (ws_size >= need && (size_t)E <= NF) {
        // ================= tier 1 =================
        unsigned* pbuf    = (unsigned*)A;
        int*      bktcnt  = cnt;
        int*      bktbase = cnt + 1024;
        int*      bcur    = cnt + 2048;
        const int cb = (E + CHUNK - 1) / CHUNK;   // 782 with CHUNK=4096
        const int gb = NN / 4;

        hipMemsetAsync(bktcnt, 0, NBK * sizeof(int), stream);
        // fused: bucket_count + transform1 (independent, overlapped)
        count_tr1_kernel<<<cb + nb, blk, 0, stream>>>(dst, E, cb, bktcnt,
                                                      x, W1, as1, ad1, H1h,
                                                      asrc, adst, NN, 128);
        scan_blocks_kernel<1024><<<1, 1024, 0, stream>>>(bktcnt, NBK, bktbase, bcur, nullptr);
        partition_kernel<<<cb, blk, 0, stream>>>(src, dst, E, bcur, pbuf);
        bucket_scatter_kernel<<<NBK, blk, 0, stream>>>(bktbase, pbuf, E, ptr, ssrc);

        // gat layer 1 + fused transform 2: H2h = relu(agg+b1)@W2 (fp16), dots (asrc2, adst2)
        gat_csr_kernel<0><<<gb, blk, 0, stream>>>(ptr, ssrc, asrc, adst, H1h, b1,
                                                  W2, nullptr, as2, ad2,
                                                  H2h, nullptr, asrc2, adst2, ET);
        // gat layer 2 + fused readout: out = relu(agg+b2)@Wr + br (fp32)
        gat_csr_kernel<1><<<gb, blk, 0, stream>>>(ptr, ssrc, asrc2, adst2, H2h, b2,
                                                  Wr, br, nullptr, nullptr,
                                                  nullptr, out, nullptr, nullptr, ET);
    } else if (ws_size >= need) {
        // ================= tier 2: per-node hist + simple scatter =================
        const int gb = NN / 4;
        init_one_kernel<<<nb1, blk, 0, stream>>>(cnt, NN);
        hist_kernel<<<(E + 255) / 256, blk, 0, stream>>>(dst, E, cnt);
        scan_blocks_kernel<256><<<nb1, blk, 0, stream>>>(cnt, NN, ptr, nullptr, bsum);
        scan_blocks_kernel<512><<<1, 512, 0, stream>>>(bsum, nb1, bsum, nullptr, nullptr);
        add_offsets_kernel<<<nb1, blk, 0, stream>>>(ptr, bsum, NN);
        copy_kernel<<<nb1, blk, 0, stream>>>(ptr, cnt, NN);
        scatter_kernel<<<(ET + 255) / 256, blk, 0, stream>>>(src, dst, E, ET, cnt, ssrc);

        transform_kernel<true, false, __half><<<nb, blk, 0, stream>>>(
            x, W1, as1, ad1, nullptr, H1h, asrc, adst, NN, 128);
        gat_csr_kernel<0><<<gb, blk, 0, stream>>>(ptr, ssrc, asrc, adst, H1h, b1,
                                                  W2, nullptr, as2, ad2,
                                                  H2h, nullptr, asrc2, adst2, ET);
        gat_csr_kernel<1><<<gb, blk, 0, stream>>>(ptr, ssrc, asrc2, adst2, H2h, b2,
                                                  Wr, br, nullptr, nullptr,
                                                  nullptr, out, nullptr, nullptr, ET);
    } else {
        // ================= tier 3: atomic path (all fp32) =================
        unsigned* m   = (unsigned*)ptr;
        float*    den = (float*)cnt;
        const int eb = (ET + 255) / 256;
        const int ab = (int)(((long)ET * FOUT + 255) / 256);

        hipMemsetAsync(A, 0, NF * sizeof(float), stream);
        hipMemsetAsync(m, 0, NN * sizeof(int), stream);
        hipMemsetAsync(den, 0, NN * sizeof(float), stream);
        transform_kernel<true, false, float><<<nb, blk, 0, stream>>>(
            x, W1, as1, ad1, nullptr, H, asrc, adst, NN, 128);
        edge_max_kernel<<<eb, blk, 0, stream>>>(src, dst, asrc, adst, m, E, ET);
        edge_denom_kernel<<<eb, blk, 0, stream>>>(src, dst, asrc, adst, m, den, E, ET);
        edge_accum_kernel<<<ab, blk, 0, stream>>>(src, dst, asrc, adst, m, den, H, A, E, ET);
        finalize_kernel<<<fb, blk, 0, stream>>>(A, b1, NN);

        transform_kernel<true, false, float><<<nb, blk, 0, stream>>>(
            A, W2, as2, ad2, nullptr, H, asrc, adst, NN, 32);
        hipMemsetAsync(A, 0, NF * sizeof(float), stream);
        hipMemsetAsync(m, 0, NN * sizeof(int), stream);
        hipMemsetAsync(den, 0, NN * sizeof(float), stream);
        edge_max_kernel<<<eb, blk, 0, stream>>>(src, dst, asrc, adst, m, E, ET);
        edge_denom_kernel<<<eb, blk, 0, stream>>>(src, dst, asrc, adst, m, den, E, ET);
        edge_accum_kernel<<<ab, blk, 0, stream>>>(src, dst, asrc, adst, m, den, H, A, E, ET);
        finalize_kernel<<<fb, blk, 0, stream>>>(A, b2, NN);

        transform_kernel<false, true, float><<<nb, blk, 0, stream>>>(
            A, Wr, nullptr, nullptr, br, out, nullptr, nullptr, NN, 32);
    }
}

// Round 15
// 279.460 us; speedup vs baseline: 1.1646x; 1.1646x over previous
//
#include <hip/hip_runtime.h>
#include <hip/hip_fp16.h>

#define NN 100000
#define NEG_SLOPE 0.2f
#define FOUT 32
#define BKT 128                       // dst-nodes per bucket
#define NBK ((NN + BKT - 1) / BKT)    // 782
#define CHUNK 8192

__device__ __forceinline__ float lrelu(float e) { return e > 0.f ? e : NEG_SLOPE * e; }

// fp16x4 load -> float4
__device__ __forceinline__ float4 ldH4(const __half* __restrict__ H, size_t idx) {
    uint2 u = *(const uint2*)(H + idx);
    float2 f01 = __half22float2(*reinterpret_cast<const __half2*>(&u.x));
    float2 f23 = __half22float2(*reinterpret_cast<const __half2*>(&u.y));
    return make_float4(f01.x, f01.y, f23.x, f23.y);
}

// ---------------- node transform (standalone; tier-2/3): h = X@W (+bias), att dots --------
template <bool ATT, bool ADD_BIAS, typename TO>
__global__ void transform_kernel(const float* __restrict__ X, const float* __restrict__ W,
                                 const float* __restrict__ att_s, const float* __restrict__ att_d,
                                 const float* __restrict__ bias,
                                 TO* __restrict__ H, float* __restrict__ a_src,
                                 float* __restrict__ a_dst, int N, int Fin) {
    __shared__ float Wl[128 * FOUT];
    __shared__ float Xl[8 * 128];
    const int t = threadIdx.x;
    const int nodeBase = blockIdx.x * 8;
    const int vprW = Fin * FOUT / 4;
    for (int i = t; i < vprW; i += 256) ((float4*)Wl)[i] = ((const float4*)W)[i];
    const int vpr = Fin / 4;
    for (int i = t; i < 8 * vpr; i += 256) {
        int r = i / vpr, c = i - r * vpr;
        int n = nodeBase + r;
        ((float4*)Xl)[i] = (n < N) ? ((const float4*)X)[(size_t)n * vpr + c]
                                   : make_float4(0.f, 0.f, 0.f, 0.f);
    }
    __syncthreads();
    const int ln = t >> 5;
    const int j  = t & 31;
    const int n  = nodeBase + ln;
    float acc = 0.f;
    for (int k = 0; k < Fin; ++k)
        acc = fmaf(Xl[ln * Fin + k], Wl[k * FOUT + j], acc);
    if (ADD_BIAS) acc += bias[j];
    if (n < N) H[(size_t)n * FOUT + j] = (TO)acc;
    if (ATT) {
        float vs = acc * att_s[j];
        float vd = acc * att_d[j];
        #pragma unroll
        for (int m = 16; m >= 1; m >>= 1) {
            vs += __shfl_xor(vs, m, 32);
            vd += __shfl_xor(vd, m, 32);
        }
        if (j == 0 && n < N) { a_src[n] = vs; a_dst[n] = vd; }
    }
}

// ---------------- fused: bucket_count (blocks < cb) + transform1 (blocks >= cb) -----------
__global__ __launch_bounds__(256)
void count_tr1_kernel(const int* __restrict__ dst, int E, int cb, int* __restrict__ bktcnt,
                      const float* __restrict__ X, const float* __restrict__ W,
                      const float* __restrict__ att_s, const float* __restrict__ att_d,
                      __half* __restrict__ H, float* __restrict__ a_src,
                      float* __restrict__ a_dst, int N, int Fin) {
    __shared__ float Wl[128 * FOUT];
    __shared__ float Xl[8 * 128];
    const int t = threadIdx.x;
    if ((int)blockIdx.x < cb) {
        int* hist = (int*)Wl;
        const int e0 = blockIdx.x * CHUNK;
        const int e1 = min(e0 + CHUNK, E);
        for (int i = t; i < NBK; i += 256) hist[i] = 0;
        __syncthreads();
        for (int i = e0 + t; i < e1; i += 256)
            atomicAdd(&hist[((unsigned)dst[i]) / BKT], 1);
        __syncthreads();
        for (int i = t; i < NBK; i += 256) {
            int h = hist[i];
            if (h) atomicAdd(&bktcnt[i], h);
        }
        return;
    }
    const int nodeBase = ((int)blockIdx.x - cb) * 8;
    const int vprW = Fin * FOUT / 4;
    for (int i = t; i < vprW; i += 256) ((float4*)Wl)[i] = ((const float4*)W)[i];
    const int vpr = Fin / 4;
    for (int i = t; i < 8 * vpr; i += 256) {
        int r = i / vpr, c = i - r * vpr;
        int n = nodeBase + r;
        ((float4*)Xl)[i] = (n < N) ? ((const float4*)X)[(size_t)n * vpr + c]
                                   : make_float4(0.f, 0.f, 0.f, 0.f);
    }
    __syncthreads();
    const int ln = t >> 5;
    const int j  = t & 31;
    const int n  = nodeBase + ln;
    float acc = 0.f;
    for (int k = 0; k < Fin; ++k)
        acc = fmaf(Xl[ln * Fin + k], Wl[k * FOUT + j], acc);
    if (n < N) H[(size_t)n * FOUT + j] = (__half)acc;
    float vs = acc * att_s[j];
    float vd = acc * att_d[j];
    #pragma unroll
    for (int m = 16; m >= 1; m >>= 1) {
        vs += __shfl_xor(vs, m, 32);
        vd += __shfl_xor(vd, m, 32);
    }
    if (j == 0 && n < N) { a_src[n] = vs; a_dst[n] = vd; }
}

// generic scan; optionally writes a second copy of the result (cursor init)
template <int BS>
__global__ void scan_blocks_kernel(const int* __restrict__ in, int n,
                                   int* __restrict__ out, int* __restrict__ out2,
                                   int* __restrict__ bsums) {
    int g = blockIdx.x * BS + threadIdx.x;
    int v = (g < n) ? in[g] : 0;
    int lane = threadIdx.x & 63;
    int w = threadIdx.x >> 6;
    int x = v;
    #pragma unroll
    for (int o = 1; o < 64; o <<= 1) {
        int y = __shfl_up(x, o, 64);
        if (lane >= o) x += y;
    }
    __shared__ int ws[BS / 64];
    if (lane == 63) ws[w] = x;
    __syncthreads();
    if (threadIdx.x == 0) {
        int a = 0;
        for (int k = 0; k < BS / 64; ++k) { int tv = ws[k]; ws[k] = a; a += tv; }
        if (bsums) bsums[blockIdx.x] = a;
    }
    __syncthreads();
    int ex = x - v + ws[w];
    if (g < n) {
        out[g] = ex;
        if (out2) out2[g] = ex;
    }
}

__global__ void add_offsets_kernel(int* __restrict__ out, const int* __restrict__ bsums, int n) {
    int g = blockIdx.x * 256 + threadIdx.x;
    if (g < n) out[g] += bsums[blockIdx.x];
}

__global__ void copy_kernel(const int* __restrict__ in, int* __restrict__ out, int n) {
    int i = blockIdx.x * blockDim.x + threadIdx.x;
    if (i < n) out[i] = in[i];
}

// pass 1: bin edges by dst bucket, packed (d_local<<17 | s), contiguous runs per (block,bucket)
__global__ __launch_bounds__(256)
void partition_kernel(const int* __restrict__ src, const int* __restrict__ dst, int E,
                      int* __restrict__ bcur, unsigned* __restrict__ pbuf) {
    __shared__ int hist[NBK];
    __shared__ int runbase[NBK];
    __shared__ int c2[NBK];
    const int tid = threadIdx.x;
    const int e0 = blockIdx.x * CHUNK;
    const int e1 = min(e0 + CHUNK, E);
    for (int t = tid; t < NBK; t += 256) { hist[t] = 0; c2[t] = 0; }
    __syncthreads();
    for (int i = e0 + tid; i < e1; i += 256)
        atomicAdd(&hist[((unsigned)dst[i]) / BKT], 1);
    __syncthreads();
    for (int t = tid; t < NBK; t += 256) {
        int h = hist[t];
        runbase[t] = h ? atomicAdd(&bcur[t], h) : 0;
    }
    __syncthreads();
    for (int i = e0 + tid; i < e1; i += 256) {
        int d = dst[i], s = src[i];
        int b = ((unsigned)d) / BKT;
        int ofs = atomicAdd(&c2[b], 1);
        pbuf[runbase[b] + ofs] = (((unsigned)(d & (BKT - 1))) << 17) | (unsigned)s;
    }
}

// pass 2: one block per bucket. Local per-node counts (LDS atomics) + LDS scan
// -> writes ptr AND ssrc (self-loop at slot 0); scatter confined to the bucket window.
__global__ __launch_bounds__(256)
void bucket_scatter_kernel(const int* __restrict__ bktbase, const unsigned* __restrict__ pbuf,
                           int E, int* __restrict__ ptr, int* __restrict__ ssrc) {
    __shared__ int lcnt[BKT];
    __shared__ int cur[BKT];
    __shared__ int wsum[4];
    const int b = blockIdx.x;
    const int tid = threadIdx.x;
    const int n0 = b * BKT;
    const int nodes = min(BKT, NN - n0);
    const int bstart = bktbase[b];
    const int bend = (b == NBK - 1) ? E : bktbase[b + 1];
    if (tid < BKT) lcnt[tid] = 0;
    __syncthreads();
    for (int i = bstart + tid; i < bend; i += 256)
        atomicAdd(&lcnt[pbuf[i] >> 17], 1);
    __syncthreads();
    int v = (tid < nodes) ? (lcnt[tid] + 1) : 0;
    int lane = tid & 63, w = tid >> 6;
    int x = v;
    #pragma unroll
    for (int o = 1; o < 64; o <<= 1) {
        int y = __shfl_up(x, o, 64);
        if (lane >= o) x += y;
    }
    if (lane == 63) wsum[w] = x;
    __syncthreads();
    if (tid == 0) {
        int a = 0;
        #pragma unroll
        for (int k = 0; k < 4; ++k) { int t2 = wsum[k]; wsum[k] = a; a += t2; }
    }
    __syncthreads();
    int ex = x - v + wsum[w];
    if (tid < nodes) {
        int p = bstart + n0 + ex;
        ptr[n0 + tid] = p;
        ssrc[p] = n0 + tid;             // self loop at slot 0
        cur[tid] = p + 1;
    }
    __syncthreads();
    for (int i = bstart + tid; i < bend; i += 256) {
        unsigned u = pbuf[i];
        int pos = atomicAdd(&cur[u >> 17], 1);
        ssrc[pos] = (int)(u & 0x1FFFFu);
    }
}

// ---------------- tier-2 helpers ----------------
__global__ void init_one_kernel(int* __restrict__ cnt, int n) {
    int i = blockIdx.x * blockDim.x + threadIdx.x;
    if (i < n) cnt[i] = 1;
}
__global__ void hist_kernel(const int* __restrict__ dst, int E, int* __restrict__ cnt) {
    int i = blockIdx.x * blockDim.x + threadIdx.x;
    if (i < E) atomicAdd(&cnt[dst[i]], 1);
}
__global__ void scatter_kernel(const int* __restrict__ src, const int* __restrict__ dst,
                               int E, int ET, int* __restrict__ cfill, int* __restrict__ ssrc) {
    int i = blockIdx.x * blockDim.x + threadIdx.x;
    if (i >= ET) return;
    int s, d;
    if (i < E) { s = src[i]; d = dst[i]; }
    else       { s = d = i - E; }
    int pos = atomicAdd(&cfill[d], 1);
    ssrc[pos] = s;
}

// ---------------- fused per-node GAT aggregation + projection (single-pass CSR gather) -----
// one 64-lane wave per node; eighth o handles edges k === o (mod 8), lane t holds
// features 4t..4t+3. Single traversal (shift-invariant softmax; |e|<~20). H fp16.
// NEW (r15): unified predicated loop with CROSS-ITERATION ssrc PREFETCH — next
// iteration's 4 s-indices load at loop top (independent of current gathers), so the
// per-phase critical path is ~L(H) instead of L(ssrc)+L(H); the old serial 1-chain
// remainder loop is folded in via clamped indices + zeroed p (bit-identical result).
// Epilogue: full-wave 32x32 projection (validated r13).
//   MODE 0 (MID):  outh = v@W2 (fp16); att dots -> oasrc/oadst
//   MODE 1 (LAST): outf = v@Wr + br (fp32 readout)
template <int MODE>
__global__ __launch_bounds__(256)
void gat_csr_kernel(const int* __restrict__ ptr, const int* __restrict__ ssrc,
                    const float* __restrict__ asrc, const float* __restrict__ adst,
                    const __half* __restrict__ H, const float* __restrict__ bias,
                    const float* __restrict__ Wp, const float* __restrict__ bp,
                    const float* __restrict__ att_s, const float* __restrict__ att_d,
                    __half* __restrict__ outh, float* __restrict__ outf,
                    float* __restrict__ oasrc, float* __restrict__ oadst, int ET) {
    __shared__ float Wl[32 * 32];
    __shared__ float hbuf[4][FOUT];
    const int tid = threadIdx.x;
    for (int i = tid; i < 1024; i += 256) Wl[i] = Wp[i];
    const int w = tid >> 6, lane = tid & 63;
    const int wid = blockIdx.x * 4 + w;
    const int beg = ptr[wid];
    const int end = (wid == NN - 1) ? ET : ptr[wid + 1];
    const int deg = end - beg;
    const int dm1 = deg - 1;
    const float ad = adst[wid];
    const int o = lane >> 3, t = lane & 7;

    float4 a0 = make_float4(0.f, 0.f, 0.f, 0.f);
    float4 a1 = make_float4(0.f, 0.f, 0.f, 0.f);
    float4 a2 = make_float4(0.f, 0.f, 0.f, 0.f);
    float4 a3 = make_float4(0.f, 0.f, 0.f, 0.f);
    float sm0 = 0.f, sm1 = 0.f;
    int k = o;
    // preamble: clamped s-loads for the first block (always address-safe, deg >= 1)
    int cs0 = ssrc[beg + min(k,      dm1)];
    int cs1 = ssrc[beg + min(k + 8,  dm1)];
    int cs2 = ssrc[beg + min(k + 16, dm1)];
    int cs3 = ssrc[beg + min(k + 24, dm1)];
    while (k < deg) {
        const int nk = k + 32;
        // prefetch next block's s (independent of this block's gathers)
        int ns0 = ssrc[beg + min(nk,      dm1)];
        int ns1 = ssrc[beg + min(nk + 8,  dm1)];
        int ns2 = ssrc[beg + min(nk + 16, dm1)];
        int ns3 = ssrc[beg + min(nk + 24, dm1)];
        float e0 = asrc[cs0], e1 = asrc[cs1], e2 = asrc[cs2], e3 = asrc[cs3];
        float4 h0 = ldH4(H, (size_t)cs0 * FOUT + 4 * t);
        float4 h1 = ldH4(H, (size_t)cs1 * FOUT + 4 * t);
        float4 h2 = ldH4(H, (size_t)cs2 * FOUT + 4 * t);
        float4 h3 = ldH4(H, (size_t)cs3 * FOUT + 4 * t);
        float p0 = __expf(lrelu(e0 + ad));                                  // k < deg in-loop
        float p1 = (k + 8  < deg) ? __expf(lrelu(e1 + ad)) : 0.f;
        float p2 = (k + 16 < deg) ? __expf(lrelu(e2 + ad)) : 0.f;
        float p3 = (k + 24 < deg) ? __expf(lrelu(e3 + ad)) : 0.f;
        sm0 += p0 + p2; sm1 += p1 + p3;
        a0.x = fmaf(p0, h0.x, a0.x); a0.y = fmaf(p0, h0.y, a0.y);
        a0.z = fmaf(p0, h0.z, a0.z); a0.w = fmaf(p0, h0.w, a0.w);
        a1.x = fmaf(p1, h1.x, a1.x); a1.y = fmaf(p1, h1.y, a1.y);
        a1.z = fmaf(p1, h1.z, a1.z); a1.w = fmaf(p1, h1.w, a1.w);
        a2.x = fmaf(p2, h2.x, a2.x); a2.y = fmaf(p2, h2.y, a2.y);
        a2.z = fmaf(p2, h2.z, a2.z); a2.w = fmaf(p2, h2.w, a2.w);
        a3.x = fmaf(p3, h3.x, a3.x); a3.y = fmaf(p3, h3.y, a3.y);
        a3.z = fmaf(p3, h3.z, a3.z); a3.w = fmaf(p3, h3.w, a3.w);
        k = nk;
        cs0 = ns0; cs1 = ns1; cs2 = ns2; cs3 = ns3;
    }
    float4 a = make_float4(a0.x + a1.x + a2.x + a3.x, a0.y + a1.y + a2.y + a3.y,
                           a0.z + a1.z + a2.z + a3.z, a0.w + a1.w + a2.w + a3.w);
    float sm = sm0 + sm1;
    #pragma unroll
    for (int off = 8; off <= 32; off <<= 1) {
        a.x += __shfl_xor(a.x, off, 64);
        a.y += __shfl_xor(a.y, off, 64);
        a.z += __shfl_xor(a.z, off, 64);
        a.w += __shfl_xor(a.w, off, 64);
        sm  += __shfl_xor(sm,  off, 64);
    }
    const float inv = 1.f / (sm + 1e-16f);

    // v = relu(agg*inv + bias) -> hbuf (8 lanes), then full-wave projection
    if (lane < 8) {
        float4 bv = *(const float4*)(bias + 4 * t);
        hbuf[w][4 * t]     = fmaxf(fmaf(a.x, inv, bv.x), 0.f);
        hbuf[w][4 * t + 1] = fmaxf(fmaf(a.y, inv, bv.y), 0.f);
        hbuf[w][4 * t + 2] = fmaxf(fmaf(a.z, inv, bv.z), 0.f);
        hbuf[w][4 * t + 3] = fmaxf(fmaf(a.w, inv, bv.w), 0.f);
    }
    __syncthreads();                 // Wl + hbuf visible (uniform barrier)
    {
        const int j = lane & 31, hh = lane >> 5;
        float r = 0.f;
        #pragma unroll
        for (int kk = 0; kk < 16; ++kk) {
            int k2 = hh * 16 + kk;
            r = fmaf(hbuf[w][k2], Wl[k2 * 32 + j], r);
        }
        r += __shfl_xor(r, 32, 64);
        if (MODE == 1) {
            if (lane < 32) outf[(size_t)wid * FOUT + j] = r + bp[j];
        } else {
            float rn = __shfl_xor(r, 1, 64);
            if (lane < 32 && !(j & 1)) {
                __half2 h2 = __float22half2_rn(make_float2(r, rn));
                *(__half2*)(outh + (size_t)wid * FOUT + j) = h2;
            }
            float vs = r * att_s[j];
            float vd = r * att_d[j];
            #pragma unroll
            for (int off = 1; off < 32; off <<= 1) {
                vs += __shfl_xor(vs, off, 64);
                vd += __shfl_xor(vd, off, 64);
            }
            if (lane == 0) { oasrc[wid] = vs; oadst[wid] = vd; }
        }
    }
}

// ---------------- tier-3 fallback (round-2 proven atomic path, all fp32) ----------------
__device__ __forceinline__ unsigned ordf(float f) {
    unsigned u = __float_as_uint(f);
    return (u & 0x80000000u) ? ~u : (u | 0x80000000u);
}
__device__ __forceinline__ float unordf(unsigned u) {
    return (u & 0x80000000u) ? __uint_as_float(u & 0x7FFFFFFFu) : __uint_as_float(~u);
}
__device__ __forceinline__ void edge_sd(int i, int E, const int* __restrict__ src,
                                        const int* __restrict__ dst, int& s, int& d) {
    if (i < E) { s = src[i]; d = dst[i]; }
    else       { s = d = i - E; }
}
__global__ void edge_max_kernel(const int* __restrict__ src, const int* __restrict__ dst,
                                const float* __restrict__ a_src, const float* __restrict__ a_dst,
                                unsigned* __restrict__ m, int E, int ET) {
    int i = blockIdx.x * blockDim.x + threadIdx.x;
    if (i >= ET) return;
    int s, d; edge_sd(i, E, src, dst, s, d);
    atomicMax(m + d, ordf(lrelu(a_src[s] + a_dst[d])));
}
__global__ void edge_denom_kernel(const int* __restrict__ src, const int* __restrict__ dst,
                                  const float* __restrict__ a_src, const float* __restrict__ a_dst,
                                  const unsigned* __restrict__ m, float* __restrict__ denom,
                                  int E, int ET) {
    int i = blockIdx.x * blockDim.x + threadIdx.x;
    if (i >= ET) return;
    int s, d; edge_sd(i, E, src, dst, s, d);
    atomicAdd(denom + d, __expf(lrelu(a_src[s] + a_dst[d]) - unordf(m[d])));
}
__global__ void edge_accum_kernel(const int* __restrict__ src, const int* __restrict__ dst,
                                  const float* __restrict__ a_src, const float* __restrict__ a_dst,
                                  const unsigned* __restrict__ m, const float* __restrict__ denom,
                                  const float* __restrict__ H, float* __restrict__ accum,
                                  int E, int ET) {
    long tid = (long)blockIdx.x * blockDim.x + threadIdx.x;
    if (tid >= (long)ET * FOUT) return;
    int i = (int)(tid >> 5);
    int j = (int)(tid & 31);
    int s, d; edge_sd(i, E, src, dst, s, d);
    float w = __expf(lrelu(a_src[s] + a_dst[d]) - unordf(m[d])) / (denom[d] + 1e-16f);
    atomicAdd(accum + (long)d * FOUT + j, w * H[(long)s * FOUT + j]);
}
__global__ void finalize_kernel(float* __restrict__ accum, const float* __restrict__ bias, int N) {
    int tid = blockIdx.x * blockDim.x + threadIdx.x;
    if (tid >= N * FOUT) return;
    int j = tid & 31;
    accum[tid] = fmaxf(accum[tid] + bias[j], 0.f);
}

extern "C" void kernel_launch(void* const* d_in, const int* in_sizes, int n_in,
                              void* d_out, int out_size, void* d_ws, size_t ws_size,
                              hipStream_t stream) {
    const float* x   = (const float*)d_in[0];
    const int*   ei  = (const int*)d_in[1];
    const float* W1  = (const float*)d_in[2];
    const float* as1 = (const float*)d_in[3];
    const float* ad1 = (const float*)d_in[4];
    const float* b1  = (const float*)d_in[5];
    const float* W2  = (const float*)d_in[6];
    const float* as2 = (const float*)d_in[7];
    const float* ad2 = (const float*)d_in[8];
    const float* b2  = (const float*)d_in[9];
    const float* Wr  = (const float*)d_in[10];
    const float* br  = (const float*)d_in[11];
    float* out = (float*)d_out;

    const int E  = in_sizes[1] / 2;
    const int*  src = ei;
    const int*  dst = ei + E;
    const int ET = E + NN;

    const size_t NF = (size_t)NN * FOUT;
    // layout (float units): A(NF) | H(NF) | asrc(NN) | adst(NN) | asrc2(NN) | adst2(NN)
    //                       | ptr(NN) | cnt(NN) | bsum(512) | ssrc(ET)
    float* A     = (float*)d_ws;
    float* H     = A + NF;
    float* asrc  = H + NF;
    float* adst  = asrc + NN;
    float* asrc2 = adst + NN;
    float* adst2 = asrc2 + NN;
    int*   ptr   = (int*)(adst2 + NN);
    int*   cnt   = ptr + NN;
    int*   bsum  = cnt + NN;
    int*   ssrc  = bsum + 512;
    __half* H1h  = (__half*)H;
    __half* H2h  = (__half*)A;
    const size_t need = (2 * NF + 6 * (size_t)NN + 512 + (size_t)ET) * 4;

    dim3 blk(256);
    const int nb  = (NN + 7) / 8;
    const int fb  = (NN * FOUT + 255) / 256;
    const int nb1 = (NN + 255) / 256;   // 391

    if (ws_size >= need && (size_t)E <= NF) {
        // ================= tier 1 =================
        unsigned* pbuf    = (unsigned*)A;
        int*      bktcnt  = cnt;
        int*      bktbase = cnt + 1024;
        int*      bcur    = cnt + 2048;
        const int cb = (E + CHUNK - 1) / CHUNK;   // 391 with CHUNK=8192
        const int gb = NN / 4;

        hipMemsetAsync(bktcnt, 0, NBK * sizeof(int), stream);
        // fused: bucket_count + transform1 (independent, overlapped)
        count_tr1_kernel<<<cb + nb, blk, 0, stream>>>(dst, E, cb, bktcnt,
                                                      x, W1, as1, ad1, H1h,
                                                      asrc, adst, NN, 128);
        scan_blocks_kernel<1024><<<1, 1024, 0, stream>>>(bktcnt, NBK, bktbase, bcur, nullptr);
        partition_kernel<<<cb, blk, 0, stream>>>(src, dst, E, bcur, pbuf);
        bucket_scatter_kernel<<<NBK, blk, 0, stream>>>(bktbase, pbuf, E, ptr, ssrc);

        // gat layer 1 + fused transform 2: H2h = relu(agg+b1)@W2 (fp16), dots (asrc2, adst2)
        gat_csr_kernel<0><<<gb, blk, 0, stream>>>(ptr, ssrc, asrc, adst, H1h, b1,
                                                  W2, nullptr, as2, ad2,
                                                  H2h, nullptr, asrc2, adst2, ET);
        // gat layer 2 + fused readout: out = relu(agg+b2)@Wr + br (fp32)
        gat_csr_kernel<1><<<gb, blk, 0, stream>>>(ptr, ssrc, asrc2, adst2, H2h, b2,
                                                  Wr, br, nullptr, nullptr,
                                                  nullptr, out, nullptr, nullptr, ET);
    } else if (ws_size >= need) {
        // ================= tier 2: per-node hist + simple scatter =================
        const int gb = NN / 4;
        init_one_kernel<<<nb1, blk, 0, stream>>>(cnt, NN);
        hist_kernel<<<(E + 255) / 256, blk, 0, stream>>>(dst, E, cnt);
        scan_blocks_kernel<256><<<nb1, blk, 0, stream>>>(cnt, NN, ptr, nullptr, bsum);
        scan_blocks_kernel<512><<<1, 512, 0, stream>>>(bsum, nb1, bsum, nullptr, nullptr);
        add_offsets_kernel<<<nb1, blk, 0, stream>>>(ptr, bsum, NN);
        copy_kernel<<<nb1, blk, 0, stream>>>(ptr, cnt, NN);
        scatter_kernel<<<(ET + 255) / 256, blk, 0, stream>>>(src, dst, E, ET, cnt, ssrc);

        transform_kernel<true, false, __half><<<nb, blk, 0, stream>>>(
            x, W1, as1, ad1, nullptr, H1h, asrc, adst, NN, 128);
        gat_csr_kernel<0><<<gb, blk, 0, stream>>>(ptr, ssrc, asrc, adst, H1h, b1,
                                                  W2, nullptr, as2, ad2,
                                                  H2h, nullptr, asrc2, adst2, ET);
        gat_csr_kernel<1><<<gb, blk, 0, stream>>>(ptr, ssrc, asrc2, adst2, H2h, b2,
                                                  Wr, br, nullptr, nullptr,
                                                  nullptr, out, nullptr, nullptr, ET);
    } else {
        // ================= tier 3: atomic path (all fp32) =================
        unsigned* m   = (unsigned*)ptr;
        float*    den = (float*)cnt;
        const int eb = (ET + 255) / 256;
        const int ab = (int)(((long)ET * FOUT + 255) / 256);

        hipMemsetAsync(A, 0, NF * sizeof(float), stream);
        hipMemsetAsync(m, 0, NN * sizeof(int), stream);
        hipMemsetAsync(den, 0, NN * sizeof(float), stream);
        transform_kernel<true, false, float><<<nb, blk, 0, stream>>>(
            x, W1, as1, ad1, nullptr, H, asrc, adst, NN, 128);
        edge_max_kernel<<<eb, blk, 0, stream>>>(src, dst, asrc, adst, m, E, ET);
        edge_denom_kernel<<<eb, blk, 0, stream>>>(src, dst, asrc, adst, m, den, E, ET);
        edge_accum_kernel<<<ab, blk, 0, stream>>>(src, dst, asrc, adst, m, den, H, A, E, ET);
        finalize_kernel<<<fb, blk, 0, stream>>>(A, b1, NN);

        transform_kernel<true, false, float><<<nb, blk, 0, stream>>>(
            A, W2, as2, ad2, nullptr, H, asrc, adst, NN, 32);
        hipMemsetAsync(A, 0, NF * sizeof(float), stream);
        hipMemsetAsync(m, 0, NN * sizeof(int), stream);
        hipMemsetAsync(den, 0, NN * sizeof(float), stream);
        edge_max_kernel<<<eb, blk, 0, stream>>>(src, dst, asrc, adst, m, E, ET);
        edge_denom_kernel<<<eb, blk, 0, stream>>>(src, dst, asrc, adst, m, den, E, ET);
        edge_accum_kernel<<<ab, blk, 0, stream>>>(src, dst, asrc, adst, m, den, H, A, E, ET);
        finalize_kernel<<<fb, blk, 0, stream>>>(A, b2, NN);

        transform_kernel<false, true, float><<<nb, blk, 0, stream>>>(
            A, Wr, nullptr, nullptr, br, out, nullptr, nullptr, NN, 32);
    }
}

// Round 16
// 273.758 us; speedup vs baseline: 1.1888x; 1.0208x over previous
//
#include <hip/hip_runtime.h>
#include <hip/hip_fp16.h>

#define NN 100000
#define NEG_SLOPE 0.2f
#define FOUT 32
#define BKT 128                       // dst-nodes per bucket
#define NBK ((NN + BKT - 1) / BKT)    // 782
#define CHUNK 8192

__device__ __forceinline__ float lrelu(float e) { return e > 0.f ? e : NEG_SLOPE * e; }

// fp16x4 load -> float4
__device__ __forceinline__ float4 ldH4(const __half* __restrict__ H, size_t idx) {
    uint2 u = *(const uint2*)(H + idx);
    float2 f01 = __half22float2(*reinterpret_cast<const __half2*>(&u.x));
    float2 f23 = __half22float2(*reinterpret_cast<const __half2*>(&u.y));
    return make_float4(f01.x, f01.y, f23.x, f23.y);
}

// ---------------- node transform (standalone; tier-2/3): h = X@W (+bias), att dots --------
template <bool ATT, bool ADD_BIAS, typename TO>
__global__ void transform_kernel(const float* __restrict__ X, const float* __restrict__ W,
                                 const float* __restrict__ att_s, const float* __restrict__ att_d,
                                 const float* __restrict__ bias,
                                 TO* __restrict__ H, float* __restrict__ a_src,
                                 float* __restrict__ a_dst, int N, int Fin) {
    __shared__ float Wl[128 * FOUT];
    __shared__ float Xl[8 * 128];
    const int t = threadIdx.x;
    const int nodeBase = blockIdx.x * 8;
    const int vprW = Fin * FOUT / 4;
    for (int i = t; i < vprW; i += 256) ((float4*)Wl)[i] = ((const float4*)W)[i];
    const int vpr = Fin / 4;
    for (int i = t; i < 8 * vpr; i += 256) {
        int r = i / vpr, c = i - r * vpr;
        int n = nodeBase + r;
        ((float4*)Xl)[i] = (n < N) ? ((const float4*)X)[(size_t)n * vpr + c]
                                   : make_float4(0.f, 0.f, 0.f, 0.f);
    }
    __syncthreads();
    const int ln = t >> 5;
    const int j  = t & 31;
    const int n  = nodeBase + ln;
    float acc = 0.f;
    for (int k = 0; k < Fin; ++k)
        acc = fmaf(Xl[ln * Fin + k], Wl[k * FOUT + j], acc);
    if (ADD_BIAS) acc += bias[j];
    if (n < N) H[(size_t)n * FOUT + j] = (TO)acc;
    if (ATT) {
        float vs = acc * att_s[j];
        float vd = acc * att_d[j];
        #pragma unroll
        for (int m = 16; m >= 1; m >>= 1) {
            vs += __shfl_xor(vs, m, 32);
            vd += __shfl_xor(vd, m, 32);
        }
        if (j == 0 && n < N) { a_src[n] = vs; a_dst[n] = vd; }
    }
}

// ---------------- fused: bucket_count (blocks < cb) + transform1 (blocks >= cb) -----------
__global__ __launch_bounds__(256)
void count_tr1_kernel(const int* __restrict__ dst, int E, int cb, int* __restrict__ bktcnt,
                      const float* __restrict__ X, const float* __restrict__ W,
                      const float* __restrict__ att_s, const float* __restrict__ att_d,
                      __half* __restrict__ H, float* __restrict__ a_src,
                      float* __restrict__ a_dst, int N, int Fin) {
    __shared__ float Wl[128 * FOUT];
    __shared__ float Xl[8 * 128];
    const int t = threadIdx.x;
    if ((int)blockIdx.x < cb) {
        int* hist = (int*)Wl;
        const int e0 = blockIdx.x * CHUNK;
        const int e1 = min(e0 + CHUNK, E);
        for (int i = t; i < NBK; i += 256) hist[i] = 0;
        __syncthreads();
        int i = e0 + t;
        for (; i + 768 < e1; i += 1024) {
            int d0 = dst[i], d1 = dst[i + 256], d2 = dst[i + 512], d3 = dst[i + 768];
            atomicAdd(&hist[((unsigned)d0) / BKT], 1);
            atomicAdd(&hist[((unsigned)d1) / BKT], 1);
            atomicAdd(&hist[((unsigned)d2) / BKT], 1);
            atomicAdd(&hist[((unsigned)d3) / BKT], 1);
        }
        for (; i < e1; i += 256)
            atomicAdd(&hist[((unsigned)dst[i]) / BKT], 1);
        __syncthreads();
        for (int q = t; q < NBK; q += 256) {
            int h = hist[q];
            if (h) atomicAdd(&bktcnt[q], h);
        }
        return;
    }
    const int nodeBase = ((int)blockIdx.x - cb) * 8;
    const int vprW = Fin * FOUT / 4;
    for (int i = t; i < vprW; i += 256) ((float4*)Wl)[i] = ((const float4*)W)[i];
    const int vpr = Fin / 4;
    for (int i = t; i < 8 * vpr; i += 256) {
        int r = i / vpr, c = i - r * vpr;
        int n = nodeBase + r;
        ((float4*)Xl)[i] = (n < N) ? ((const float4*)X)[(size_t)n * vpr + c]
                                   : make_float4(0.f, 0.f, 0.f, 0.f);
    }
    __syncthreads();
    const int ln = t >> 5;
    const int j  = t & 31;
    const int n  = nodeBase + ln;
    float acc = 0.f;
    for (int k = 0; k < Fin; ++k)
        acc = fmaf(Xl[ln * Fin + k], Wl[k * FOUT + j], acc);
    if (n < N) H[(size_t)n * FOUT + j] = (__half)acc;
    float vs = acc * att_s[j];
    float vd = acc * att_d[j];
    #pragma unroll
    for (int m = 16; m >= 1; m >>= 1) {
        vs += __shfl_xor(vs, m, 32);
        vd += __shfl_xor(vd, m, 32);
    }
    if (j == 0 && n < N) { a_src[n] = vs; a_dst[n] = vd; }
}

// generic scan; optionally writes a second copy of the result (cursor init)
template <int BS>
__global__ void scan_blocks_kernel(const int* __restrict__ in, int n,
                                   int* __restrict__ out, int* __restrict__ out2,
                                   int* __restrict__ bsums) {
    int g = blockIdx.x * BS + threadIdx.x;
    int v = (g < n) ? in[g] : 0;
    int lane = threadIdx.x & 63;
    int w = threadIdx.x >> 6;
    int x = v;
    #pragma unroll
    for (int o = 1; o < 64; o <<= 1) {
        int y = __shfl_up(x, o, 64);
        if (lane >= o) x += y;
    }
    __shared__ int ws[BS / 64];
    if (lane == 63) ws[w] = x;
    __syncthreads();
    if (threadIdx.x == 0) {
        int a = 0;
        for (int k = 0; k < BS / 64; ++k) { int tv = ws[k]; ws[k] = a; a += tv; }
        if (bsums) bsums[blockIdx.x] = a;
    }
    __syncthreads();
    int ex = x - v + ws[w];
    if (g < n) {
        out[g] = ex;
        if (out2) out2[g] = ex;
    }
}

__global__ void add_offsets_kernel(int* __restrict__ out, const int* __restrict__ bsums, int n) {
    int g = blockIdx.x * 256 + threadIdx.x;
    if (g < n) out[g] += bsums[blockIdx.x];
}

__global__ void copy_kernel(const int* __restrict__ in, int* __restrict__ out, int n) {
    int i = blockIdx.x * blockDim.x + threadIdx.x;
    if (i < n) out[i] = in[i];
}

// pass 1: bin edges by dst bucket, packed (d_local<<17 | s); streaming loops 4x unrolled
__global__ __launch_bounds__(256)
void partition_kernel(const int* __restrict__ src, const int* __restrict__ dst, int E,
                      int* __restrict__ bcur, unsigned* __restrict__ pbuf) {
    __shared__ int hist[NBK];
    __shared__ int runbase[NBK];
    __shared__ int c2[NBK];
    const int tid = threadIdx.x;
    const int e0 = blockIdx.x * CHUNK;
    const int e1 = min(e0 + CHUNK, E);
    for (int t = tid; t < NBK; t += 256) { hist[t] = 0; c2[t] = 0; }
    __syncthreads();
    int i = e0 + tid;
    for (; i + 768 < e1; i += 1024) {
        int d0 = dst[i], d1 = dst[i + 256], d2 = dst[i + 512], d3 = dst[i + 768];
        atomicAdd(&hist[((unsigned)d0) / BKT], 1);
        atomicAdd(&hist[((unsigned)d1) / BKT], 1);
        atomicAdd(&hist[((unsigned)d2) / BKT], 1);
        atomicAdd(&hist[((unsigned)d3) / BKT], 1);
    }
    for (; i < e1; i += 256)
        atomicAdd(&hist[((unsigned)dst[i]) / BKT], 1);
    __syncthreads();
    for (int t = tid; t < NBK; t += 256) {
        int h = hist[t];
        runbase[t] = h ? atomicAdd(&bcur[t], h) : 0;
    }
    __syncthreads();
    i = e0 + tid;
    for (; i + 768 < e1; i += 1024) {
        int d0 = dst[i], d1 = dst[i + 256], d2 = dst[i + 512], d3 = dst[i + 768];
        int s0 = src[i], s1 = src[i + 256], s2 = src[i + 512], s3 = src[i + 768];
        { int b = ((unsigned)d0) / BKT; int ofs = atomicAdd(&c2[b], 1);
          pbuf[runbase[b] + ofs] = (((unsigned)(d0 & (BKT - 1))) << 17) | (unsigned)s0; }
        { int b = ((unsigned)d1) / BKT; int ofs = atomicAdd(&c2[b], 1);
          pbuf[runbase[b] + ofs] = (((unsigned)(d1 & (BKT - 1))) << 17) | (unsigned)s1; }
        { int b = ((unsigned)d2) / BKT; int ofs = atomicAdd(&c2[b], 1);
          pbuf[runbase[b] + ofs] = (((unsigned)(d2 & (BKT - 1))) << 17) | (unsigned)s2; }
        { int b = ((unsigned)d3) / BKT; int ofs = atomicAdd(&c2[b], 1);
          pbuf[runbase[b] + ofs] = (((unsigned)(d3 & (BKT - 1))) << 17) | (unsigned)s3; }
    }
    for (; i < e1; i += 256) {
        int d = dst[i], s = src[i];
        int b = ((unsigned)d) / BKT;
        int ofs = atomicAdd(&c2[b], 1);
        pbuf[runbase[b] + ofs] = (((unsigned)(d & (BKT - 1))) << 17) | (unsigned)s;
    }
}

// pass 2: one block per bucket; streaming loops 4x unrolled
__global__ __launch_bounds__(256)
void bucket_scatter_kernel(const int* __restrict__ bktbase, const unsigned* __restrict__ pbuf,
                           int E, int* __restrict__ ptr, int* __restrict__ ssrc) {
    __shared__ int lcnt[BKT];
    __shared__ int cur[BKT];
    __shared__ int wsum[4];
    const int b = blockIdx.x;
    const int tid = threadIdx.x;
    const int n0 = b * BKT;
    const int nodes = min(BKT, NN - n0);
    const int bstart = bktbase[b];
    const int bend = (b == NBK - 1) ? E : bktbase[b + 1];
    if (tid < BKT) lcnt[tid] = 0;
    __syncthreads();
    int i = bstart + tid;
    for (; i + 768 < bend; i += 1024) {
        unsigned u0 = pbuf[i], u1 = pbuf[i + 256], u2 = pbuf[i + 512], u3 = pbuf[i + 768];
        atomicAdd(&lcnt[u0 >> 17], 1);
        atomicAdd(&lcnt[u1 >> 17], 1);
        atomicAdd(&lcnt[u2 >> 17], 1);
        atomicAdd(&lcnt[u3 >> 17], 1);
    }
    for (; i < bend; i += 256)
        atomicAdd(&lcnt[pbuf[i] >> 17], 1);
    __syncthreads();
    int v = (tid < nodes) ? (lcnt[tid] + 1) : 0;
    int lane = tid & 63, w = tid >> 6;
    int x = v;
    #pragma unroll
    for (int o = 1; o < 64; o <<= 1) {
        int y = __shfl_up(x, o, 64);
        if (lane >= o) x += y;
    }
    if (lane == 63) wsum[w] = x;
    __syncthreads();
    if (tid == 0) {
        int a = 0;
        #pragma unroll
        for (int k = 0; k < 4; ++k) { int t2 = wsum[k]; wsum[k] = a; a += t2; }
    }
    __syncthreads();
    int ex = x - v + wsum[w];
    if (tid < nodes) {
        int p = bstart + n0 + ex;
        ptr[n0 + tid] = p;
        ssrc[p] = n0 + tid;             // self loop at slot 0
        cur[tid] = p + 1;
    }
    __syncthreads();
    i = bstart + tid;
    for (; i + 768 < bend; i += 1024) {
        unsigned u0 = pbuf[i], u1 = pbuf[i + 256], u2 = pbuf[i + 512], u3 = pbuf[i + 768];
        { int pos = atomicAdd(&cur[u0 >> 17], 1); ssrc[pos] = (int)(u0 & 0x1FFFFu); }
        { int pos = atomicAdd(&cur[u1 >> 17], 1); ssrc[pos] = (int)(u1 & 0x1FFFFu); }
        { int pos = atomicAdd(&cur[u2 >> 17], 1); ssrc[pos] = (int)(u2 & 0x1FFFFu); }
        { int pos = atomicAdd(&cur[u3 >> 17], 1); ssrc[pos] = (int)(u3 & 0x1FFFFu); }
    }
    for (; i < bend; i += 256) {
        unsigned u = pbuf[i];
        int pos = atomicAdd(&cur[u >> 17], 1);
        ssrc[pos] = (int)(u & 0x1FFFFu);
    }
}

// ---------------- tier-2 helpers ----------------
__global__ void init_one_kernel(int* __restrict__ cnt, int n) {
    int i = blockIdx.x * blockDim.x + threadIdx.x;
    if (i < n) cnt[i] = 1;
}
__global__ void hist_kernel(const int* __restrict__ dst, int E, int* __restrict__ cnt) {
    int i = blockIdx.x * blockDim.x + threadIdx.x;
    if (i < E) atomicAdd(&cnt[dst[i]], 1);
}
__global__ void scatter_kernel(const int* __restrict__ src, const int* __restrict__ dst,
                               int E, int ET, int* __restrict__ cfill, int* __restrict__ ssrc) {
    int i = blockIdx.x * blockDim.x + threadIdx.x;
    if (i >= ET) return;
    int s, d;
    if (i < E) { s = src[i]; d = dst[i]; }
    else       { s = d = i - E; }
    int pos = atomicAdd(&cfill[d], 1);
    ssrc[pos] = s;
}

// ---------------- fused per-node GAT aggregation + projection (single-pass CSR gather) -----
// one 64-lane wave per node; eighth o handles edges k === o (mod 8), lane t holds
// features 4t..4t+3. Single traversal + cross-iteration ssrc prefetch (r15).
// NEW (r16): BARRIER-FREE epilogue — a/sm are uniform per t-class after the xor{8,16,32}
// reduce, so ALL lanes compute v = relu(a*inv+bias); the 32x32 projection reads v via
// 16 register shuffles (srcLane = hh*4+q, static component) instead of an LDS round trip.
// Single __syncthreads at kernel top (Wl visibility only).
//   MODE 0 (MID):  outh = v@W2 (fp16); att dots -> oasrc/oadst
//   MODE 1 (LAST): outf = v@Wr + br (fp32 readout)
template <int MODE>
__global__ __launch_bounds__(256)
void gat_csr_kernel(const int* __restrict__ ptr, const int* __restrict__ ssrc,
                    const float* __restrict__ asrc, const float* __restrict__ adst,
                    const __half* __restrict__ H, const float* __restrict__ bias,
                    const float* __restrict__ Wp, const float* __restrict__ bp,
                    const float* __restrict__ att_s, const float* __restrict__ att_d,
                    __half* __restrict__ outh, float* __restrict__ outf,
                    float* __restrict__ oasrc, float* __restrict__ oadst, int ET) {
    __shared__ float Wl[32 * 32];
    const int tid = threadIdx.x;
    for (int i = tid; i < 1024; i += 256) Wl[i] = Wp[i];
    __syncthreads();                 // Wl visible; only barrier in the kernel
    const int w = tid >> 6, lane = tid & 63;
    (void)w;
    const int wid = blockIdx.x * 4 + (tid >> 6);
    const int beg = ptr[wid];
    const int end = (wid == NN - 1) ? ET : ptr[wid + 1];
    const int deg = end - beg;
    const int dm1 = deg - 1;
    const float ad = adst[wid];
    const int o = lane >> 3, t = lane & 7;

    float4 a0 = make_float4(0.f, 0.f, 0.f, 0.f);
    float4 a1 = make_float4(0.f, 0.f, 0.f, 0.f);
    float4 a2 = make_float4(0.f, 0.f, 0.f, 0.f);
    float4 a3 = make_float4(0.f, 0.f, 0.f, 0.f);
    float sm0 = 0.f, sm1 = 0.f;
    int k = o;
    int cs0 = ssrc[beg + min(k,      dm1)];
    int cs1 = ssrc[beg + min(k + 8,  dm1)];
    int cs2 = ssrc[beg + min(k + 16, dm1)];
    int cs3 = ssrc[beg + min(k + 24, dm1)];
    while (k < deg) {
        const int nk = k + 32;
        int ns0 = ssrc[beg + min(nk,      dm1)];
        int ns1 = ssrc[beg + min(nk + 8,  dm1)];
        int ns2 = ssrc[beg + min(nk + 16, dm1)];
        int ns3 = ssrc[beg + min(nk + 24, dm1)];
        float e0 = asrc[cs0], e1 = asrc[cs1], e2 = asrc[cs2], e3 = asrc[cs3];
        float4 h0 = ldH4(H, (size_t)cs0 * FOUT + 4 * t);
        float4 h1 = ldH4(H, (size_t)cs1 * FOUT + 4 * t);
        float4 h2 = ldH4(H, (size_t)cs2 * FOUT + 4 * t);
        float4 h3 = ldH4(H, (size_t)cs3 * FOUT + 4 * t);
        float p0 = __expf(lrelu(e0 + ad));
        float p1 = (k + 8  < deg) ? __expf(lrelu(e1 + ad)) : 0.f;
        float p2 = (k + 16 < deg) ? __expf(lrelu(e2 + ad)) : 0.f;
        float p3 = (k + 24 < deg) ? __expf(lrelu(e3 + ad)) : 0.f;
        sm0 += p0 + p2; sm1 += p1 + p3;
        a0.x = fmaf(p0, h0.x, a0.x); a0.y = fmaf(p0, h0.y, a0.y);
        a0.z = fmaf(p0, h0.z, a0.z); a0.w = fmaf(p0, h0.w, a0.w);
        a1.x = fmaf(p1, h1.x, a1.x); a1.y = fmaf(p1, h1.y, a1.y);
        a1.z = fmaf(p1, h1.z, a1.z); a1.w = fmaf(p1, h1.w, a1.w);
        a2.x = fmaf(p2, h2.x, a2.x); a2.y = fmaf(p2, h2.y, a2.y);
        a2.z = fmaf(p2, h2.z, a2.z); a2.w = fmaf(p2, h2.w, a2.w);
        a3.x = fmaf(p3, h3.x, a3.x); a3.y = fmaf(p3, h3.y, a3.y);
        a3.z = fmaf(p3, h3.z, a3.z); a3.w = fmaf(p3, h3.w, a3.w);
        k = nk;
        cs0 = ns0; cs1 = ns1; cs2 = ns2; cs3 = ns3;
    }
    float4 a = make_float4(a0.x + a1.x + a2.x + a3.x, a0.y + a1.y + a2.y + a3.y,
                           a0.z + a1.z + a2.z + a3.z, a0.w + a1.w + a2.w + a3.w);
    float sm = sm0 + sm1;
    #pragma unroll
    for (int off = 8; off <= 32; off <<= 1) {
        a.x += __shfl_xor(a.x, off, 64);
        a.y += __shfl_xor(a.y, off, 64);
        a.z += __shfl_xor(a.z, off, 64);
        a.w += __shfl_xor(a.w, off, 64);
        sm  += __shfl_xor(sm,  off, 64);
    }
    const float inv = 1.f / (sm + 1e-16f);

    // all lanes: v = relu(a*inv + bias) for features 4t..4t+3 (a uniform per t-class)
    float4 bv = *(const float4*)(bias + 4 * t);
    float4 vv;
    vv.x = fmaxf(fmaf(a.x, inv, bv.x), 0.f);
    vv.y = fmaxf(fmaf(a.y, inv, bv.y), 0.f);
    vv.z = fmaxf(fmaf(a.z, inv, bv.z), 0.f);
    vv.w = fmaxf(fmaf(a.w, inv, bv.w), 0.f);

    // full-wave 32x32 projection via register shuffles (no LDS, no barrier)
    const int j = lane & 31, hh = lane >> 5;
    const int base = hh << 2;
    float r = 0.f;
    #pragma unroll
    for (int q = 0; q < 4; ++q) {
        float vx = __shfl(vv.x, base + q, 64);
        float vy = __shfl(vv.y, base + q, 64);
        float vz = __shfl(vv.z, base + q, 64);
        float vw = __shfl(vv.w, base + q, 64);
        const int k2 = (hh << 4) + (q << 2);
        r = fmaf(vx, Wl[(k2 + 0) * 32 + j], r);
        r = fmaf(vy, Wl[(k2 + 1) * 32 + j], r);
        r = fmaf(vz, Wl[(k2 + 2) * 32 + j], r);
        r = fmaf(vw, Wl[(k2 + 3) * 32 + j], r);
    }
    r += __shfl_xor(r, 32, 64);
    if (MODE == 1) {
        if (lane < 32) outf[(size_t)wid * FOUT + j] = r + bp[j];
    } else {
        float rn = __shfl_xor(r, 1, 64);
        if (lane < 32 && !(j & 1)) {
            __half2 h2 = __float22half2_rn(make_float2(r, rn));
            *(__half2*)(outh + (size_t)wid * FOUT + j) = h2;
        }
        float vs = r * att_s[j];
        float vd = r * att_d[j];
        #pragma unroll
        for (int off = 1; off < 32; off <<= 1) {
            vs += __shfl_xor(vs, off, 64);
            vd += __shfl_xor(vd, off, 64);
        }
        if (lane == 0) { oasrc[wid] = vs; oadst[wid] = vd; }
    }
}

// ---------------- tier-3 fallback (round-2 proven atomic path, all fp32) ----------------
__device__ __forceinline__ unsigned ordf(float f) {
    unsigned u = __float_as_uint(f);
    return (u & 0x80000000u) ? ~u : (u | 0x80000000u);
}
__device__ __forceinline__ float unordf(unsigned u) {
    return (u & 0x80000000u) ? __uint_as_float(u & 0x7FFFFFFFu) : __uint_as_float(~u);
}
__device__ __forceinline__ void edge_sd(int i, int E, const int* __restrict__ src,
                                        const int* __restrict__ dst, int& s, int& d) {
    if (i < E) { s = src[i]; d = dst[i]; }
    else       { s = d = i - E; }
}
__global__ void edge_max_kernel(const int* __restrict__ src, const int* __restrict__ dst,
                                const float* __restrict__ a_src, const float* __restrict__ a_dst,
                                unsigned* __restrict__ m, int E, int ET) {
    int i = blockIdx.x * blockDim.x + threadIdx.x;
    if (i >= ET) return;
    int s, d; edge_sd(i, E, src, dst, s, d);
    atomicMax(m + d, ordf(lrelu(a_src[s] + a_dst[d])));
}
__global__ void edge_denom_kernel(const int* __restrict__ src, const int* __restrict__ dst,
                                  const float* __restrict__ a_src, const float* __restrict__ a_dst,
                                  const unsigned* __restrict__ m, float* __restrict__ denom,
                                  int E, int ET) {
    int i = blockIdx.x * blockDim.x + threadIdx.x;
    if (i >= ET) return;
    int s, d; edge_sd(i, E, src, dst, s, d);
    atomicAdd(denom + d, __expf(lrelu(a_src[s] + a_dst[d]) - unordf(m[d])));
}
__global__ void edge_accum_kernel(const int* __restrict__ src, const int* __restrict__ dst,
                                  const float* __restrict__ a_src, const float* __restrict__ a_dst,
                                  const unsigned* __restrict__ m, const float* __restrict__ denom,
                                  const float* __restrict__ H, float* __restrict__ accum,
                                  int E, int ET) {
    long tid = (long)blockIdx.x * blockDim.x + threadIdx.x;
    if (tid >= (long)ET * FOUT) return;
    int i = (int)(tid >> 5);
    int j = (int)(tid & 31);
    int s, d; edge_sd(i, E, src, dst, s, d);
    float w = __expf(lrelu(a_src[s] + a_dst[d]) - unordf(m[d])) / (denom[d] + 1e-16f);
    atomicAdd(accum + (long)d * FOUT + j, w * H[(long)s * FOUT + j]);
}
__global__ void finalize_kernel(float* __restrict__ accum, const float* __restrict__ bias, int N) {
    int tid = blockIdx.x * blockDim.x + threadIdx.x;
    if (tid >= N * FOUT) return;
    int j = tid & 31;
    accum[tid] = fmaxf(accum[tid] + bias[j], 0.f);
}

extern "C" void kernel_launch(void* const* d_in, const int* in_sizes, int n_in,
                              void* d_out, int out_size, void* d_ws, size_t ws_size,
                              hipStream_t stream) {
    const float* x   = (const float*)d_in[0];
    const int*   ei  = (const int*)d_in[1];
    const float* W1  = (const float*)d_in[2];
    const float* as1 = (const float*)d_in[3];
    const float* ad1 = (const float*)d_in[4];
    const float* b1  = (const float*)d_in[5];
    const float* W2  = (const float*)d_in[6];
    const float* as2 = (const float*)d_in[7];
    const float* ad2 = (const float*)d_in[8];
    const float* b2  = (const float*)d_in[9];
    const float* Wr  = (const float*)d_in[10];
    const float* br  = (const float*)d_in[11];
    float* out = (float*)d_out;

    const int E  = in_sizes[1] / 2;
    const int*  src = ei;
    const int*  dst = ei + E;
    const int ET = E + NN;

    const size_t NF = (size_t)NN * FOUT;
    // layout (float units): A(NF) | H(NF) | asrc(NN) | adst(NN) | asrc2(NN) | adst2(NN)
    //                       | ptr(NN) | cnt(NN) | bsum(512) | ssrc(ET)
    float* A     = (float*)d_ws;
    float* H     = A + NF;
    float* asrc  = H + NF;
    float* adst  = asrc + NN;
    float* asrc2 = adst + NN;
    float* adst2 = asrc2 + NN;
    int*   ptr   = (int*)(adst2 + NN);
    int*   cnt   = ptr + NN;
    int*   bsum  = cnt + NN;
    int*   ssrc  = bsum + 512;
    __half* H1h  = (__half*)H;
    __half* H2h  = (__half*)A;
    const size_t need = (2 * NF + 6 * (size_t)NN + 512 + (size_t)ET) * 4;

    dim3 blk(256);
    const int nb  = (NN + 7) / 8;
    const int fb  = (NN * FOUT + 255) / 256;
    const int nb1 = (NN + 255) / 256;   // 391

    if (ws_size >= need && (size_t)E <= NF) {
        // ================= tier 1 =================
        unsigned* pbuf    = (unsigned*)A;
        int*      bktcnt  = cnt;
        int*      bktbase = cnt + 1024;
        int*      bcur    = cnt + 2048;
        const int cb = (E + CHUNK - 1) / CHUNK;   // 391 with CHUNK=8192
        const int gb = NN / 4;

        hipMemsetAsync(bktcnt, 0, NBK * sizeof(int), stream);
        count_tr1_kernel<<<cb + nb, blk, 0, stream>>>(dst, E, cb, bktcnt,
                                                      x, W1, as1, ad1, H1h,
                                                      asrc, adst, NN, 128);
        scan_blocks_kernel<1024><<<1, 1024, 0, stream>>>(bktcnt, NBK, bktbase, bcur, nullptr);
        partition_kernel<<<cb, blk, 0, stream>>>(src, dst, E, bcur, pbuf);
        bucket_scatter_kernel<<<NBK, blk, 0, stream>>>(bktbase, pbuf, E, ptr, ssrc);

        gat_csr_kernel<0><<<gb, blk, 0, stream>>>(ptr, ssrc, asrc, adst, H1h, b1,
                                                  W2, nullptr, as2, ad2,
                                                  H2h, nullptr, asrc2, adst2, ET);
        gat_csr_kernel<1><<<gb, blk, 0, stream>>>(ptr, ssrc, asrc2, adst2, H2h, b2,
                                                  Wr, br, nullptr, nullptr,
                                                  nullptr, out, nullptr, nullptr, ET);
    } else if (ws_size >= need) {
        // ================= tier 2: per-node hist + simple scatter =================
        const int gb = NN / 4;
        init_one_kernel<<<nb1, blk, 0, stream>>>(cnt, NN);
        hist_kernel<<<(E + 255) / 256, blk, 0, stream>>>(dst, E, cnt);
        scan_blocks_kernel<256><<<nb1, blk, 0, stream>>>(cnt, NN, ptr, nullptr, bsum);
        scan_blocks_kernel<512><<<1, 512, 0, stream>>>(bsum, nb1, bsum, nullptr, nullptr);
        add_offsets_kernel<<<nb1, blk, 0, stream>>>(ptr, bsum, NN);
        copy_kernel<<<nb1, blk, 0, stream>>>(ptr, cnt, NN);
        scatter_kernel<<<(ET + 255) / 256, blk, 0, stream>>>(src, dst, E, ET, cnt, ssrc);

        transform_kernel<true, false, __half><<<nb, blk, 0, stream>>>(
            x, W1, as1, ad1, nullptr, H1h, asrc, adst, NN, 128);
        gat_csr_kernel<0><<<gb, blk, 0, stream>>>(ptr, ssrc, asrc, adst, H1h, b1,
                                                  W2, nullptr, as2, ad2,
                                                  H2h, nullptr, asrc2, adst2, ET);
        gat_csr_kernel<1><<<gb, blk, 0, stream>>>(ptr, ssrc, asrc2, adst2, H2h, b2,
                                                  Wr, br, nullptr, nullptr,
                                                  nullptr, out, nullptr, nullptr, ET);
    } else {
        // ================= tier 3: atomic path (all fp32) =================
        unsigned* m   = (unsigned*)ptr;
        float*    den = (float*)cnt;
        const int eb = (ET + 255) / 256;
        const int ab = (int)(((long)ET * FOUT + 255) / 256);

        hipMemsetAsync(A, 0, NF * sizeof(float), stream);
        hipMemsetAsync(m, 0, NN * sizeof(int), stream);
        hipMemsetAsync(den, 0, NN * sizeof(float), stream);
        transform_kernel<true, false, float><<<nb, blk, 0, stream>>>(
            x, W1, as1, ad1, nullptr, H, asrc, adst, NN, 128);
        edge_max_kernel<<<eb, blk, 0, stream>>>(src, dst, asrc, adst, m, E, ET);
        edge_denom_kernel<<<eb, blk, 0, stream>>>(src, dst, asrc, adst, m, den, E, ET);
        edge_accum_kernel<<<ab, blk, 0, stream>>>(src, dst, asrc, adst, m, den, H, A, E, ET);
        finalize_kernel<<<fb, blk, 0, stream>>>(A, b1, NN);

        transform_kernel<true, false, float><<<nb, blk, 0, stream>>>(
            A, W2, as2, ad2, nullptr, H, asrc, adst, NN, 32);
        hipMemsetAsync(A, 0, NF * sizeof(float), stream);
        hipMemsetAsync(m, 0, NN * sizeof(int), stream);
        hipMemsetAsync(den, 0, NN * sizeof(float), stream);
        edge_max_kernel<<<eb, blk, 0, stream>>>(src, dst, asrc, adst, m, E, ET);
        edge_denom_kernel<<<eb, blk, 0, stream>>>(src, dst, asrc, adst, m, den, E, ET);
        edge_accum_kernel<<<ab, blk, 0, stream>>>(src, dst, asrc, adst, m, den, H, A, E, ET);
        finalize_kernel<<<fb, blk, 0, stream>>>(A, b2, NN);

        transform_kernel<false, true, float><<<nb, blk, 0, stream>>>(
            A, Wr, nullptr, nullptr, br, out, nullptr, nullptr, NN, 32);
    }
}

// Round 17
// 270.790 us; speedup vs baseline: 1.2019x; 1.0110x over previous
//
#include <hip/hip_runtime.h>
#include <hip/hip_fp16.h>

#define NN 100000
#define NEG_SLOPE 0.2f
#define FOUT 32
#define BKT 128                       // dst-nodes per bucket
#define NBK ((NN + BKT - 1) / BKT)    // 782
#define CHUNK 8192

__device__ __forceinline__ float lrelu(float e) { return e > 0.f ? e : NEG_SLOPE * e; }

// fp16x4 load -> float4
__device__ __forceinline__ float4 ldH4(const __half* __restrict__ H, size_t idx) {
    uint2 u = *(const uint2*)(H + idx);
    float2 f01 = __half22float2(*reinterpret_cast<const __half2*>(&u.x));
    float2 f23 = __half22float2(*reinterpret_cast<const __half2*>(&u.y));
    return make_float4(f01.x, f01.y, f23.x, f23.y);
}

// ---------------- node transform (standalone; tier-2/3): h = X@W (+bias), att dots --------
template <bool ATT, bool ADD_BIAS, typename TO>
__global__ void transform_kernel(const float* __restrict__ X, const float* __restrict__ W,
                                 const float* __restrict__ att_s, const float* __restrict__ att_d,
                                 const float* __restrict__ bias,
                                 TO* __restrict__ H, float* __restrict__ a_src,
                                 float* __restrict__ a_dst, int N, int Fin) {
    __shared__ float Wl[128 * FOUT];
    __shared__ float Xl[8 * 128];
    const int t = threadIdx.x;
    const int nodeBase = blockIdx.x * 8;
    const int vprW = Fin * FOUT / 4;
    for (int i = t; i < vprW; i += 256) ((float4*)Wl)[i] = ((const float4*)W)[i];
    const int vpr = Fin / 4;
    for (int i = t; i < 8 * vpr; i += 256) {
        int r = i / vpr, c = i - r * vpr;
        int n = nodeBase + r;
        ((float4*)Xl)[i] = (n < N) ? ((const float4*)X)[(size_t)n * vpr + c]
                                   : make_float4(0.f, 0.f, 0.f, 0.f);
    }
    __syncthreads();
    const int ln = t >> 5;
    const int j  = t & 31;
    const int n  = nodeBase + ln;
    float acc = 0.f;
    for (int k = 0; k < Fin; ++k)
        acc = fmaf(Xl[ln * Fin + k], Wl[k * FOUT + j], acc);
    if (ADD_BIAS) acc += bias[j];
    if (n < N) H[(size_t)n * FOUT + j] = (TO)acc;
    if (ATT) {
        float vs = acc * att_s[j];
        float vd = acc * att_d[j];
        #pragma unroll
        for (int m = 16; m >= 1; m >>= 1) {
            vs += __shfl_xor(vs, m, 32);
            vd += __shfl_xor(vd, m, 32);
        }
        if (j == 0 && n < N) { a_src[n] = vs; a_dst[n] = vd; }
    }
}

// ---------------- fused: bucket_count (blocks < cb) + transform1 (blocks >= cb) -----------
__global__ __launch_bounds__(256)
void count_tr1_kernel(const int* __restrict__ dst, int E, int cb, int* __restrict__ bktcnt,
                      const float* __restrict__ X, const float* __restrict__ W,
                      const float* __restrict__ att_s, const float* __restrict__ att_d,
                      __half* __restrict__ H, float* __restrict__ a_src,
                      float* __restrict__ a_dst, int N, int Fin) {
    __shared__ float Wl[128 * FOUT];
    __shared__ float Xl[8 * 128];
    const int t = threadIdx.x;
    if ((int)blockIdx.x < cb) {
        int* hist = (int*)Wl;
        const int e0 = blockIdx.x * CHUNK;
        const int e1 = min(e0 + CHUNK, E);
        for (int i = t; i < NBK; i += 256) hist[i] = 0;
        __syncthreads();
        int i = e0 + t;
        for (; i + 768 < e1; i += 1024) {
            int d0 = dst[i], d1 = dst[i + 256], d2 = dst[i + 512], d3 = dst[i + 768];
            atomicAdd(&hist[((unsigned)d0) / BKT], 1);
            atomicAdd(&hist[((unsigned)d1) / BKT], 1);
            atomicAdd(&hist[((unsigned)d2) / BKT], 1);
            atomicAdd(&hist[((unsigned)d3) / BKT], 1);
        }
        for (; i < e1; i += 256)
            atomicAdd(&hist[((unsigned)dst[i]) / BKT], 1);
        __syncthreads();
        for (int q = t; q < NBK; q += 256) {
            int h = hist[q];
            if (h) atomicAdd(&bktcnt[q], h);
        }
        return;
    }
    const int nodeBase = ((int)blockIdx.x - cb) * 8;
    const int vprW = Fin * FOUT / 4;
    for (int i = t; i < vprW; i += 256) ((float4*)Wl)[i] = ((const float4*)W)[i];
    const int vpr = Fin / 4;
    for (int i = t; i < 8 * vpr; i += 256) {
        int r = i / vpr, c = i - r * vpr;
        int n = nodeBase + r;
        ((float4*)Xl)[i] = (n < N) ? ((const float4*)X)[(size_t)n * vpr + c]
                                   : make_float4(0.f, 0.f, 0.f, 0.f);
    }
    __syncthreads();
    const int ln = t >> 5;
    const int j  = t & 31;
    const int n  = nodeBase + ln;
    float acc = 0.f;
    for (int k = 0; k < Fin; ++k)
        acc = fmaf(Xl[ln * Fin + k], Wl[k * FOUT + j], acc);
    if (n < N) H[(size_t)n * FOUT + j] = (__half)acc;
    float vs = acc * att_s[j];
    float vd = acc * att_d[j];
    #pragma unroll
    for (int m = 16; m >= 1; m >>= 1) {
        vs += __shfl_xor(vs, m, 32);
        vd += __shfl_xor(vd, m, 32);
    }
    if (j == 0 && n < N) { a_src[n] = vs; a_dst[n] = vd; }
}

// generic scan; optionally writes a second copy of the result (cursor init)
template <int BS>
__global__ void scan_blocks_kernel(const int* __restrict__ in, int n,
                                   int* __restrict__ out, int* __restrict__ out2,
                                   int* __restrict__ bsums) {
    int g = blockIdx.x * BS + threadIdx.x;
    int v = (g < n) ? in[g] : 0;
    int lane = threadIdx.x & 63;
    int w = threadIdx.x >> 6;
    int x = v;
    #pragma unroll
    for (int o = 1; o < 64; o <<= 1) {
        int y = __shfl_up(x, o, 64);
        if (lane >= o) x += y;
    }
    __shared__ int ws[BS / 64];
    if (lane == 63) ws[w] = x;
    __syncthreads();
    if (threadIdx.x == 0) {
        int a = 0;
        for (int k = 0; k < BS / 64; ++k) { int tv = ws[k]; ws[k] = a; a += tv; }
        if (bsums) bsums[blockIdx.x] = a;
    }
    __syncthreads();
    int ex = x - v + ws[w];
    if (g < n) {
        out[g] = ex;
        if (out2) out2[g] = ex;
    }
}

__global__ void add_offsets_kernel(int* __restrict__ out, const int* __restrict__ bsums, int n) {
    int g = blockIdx.x * 256 + threadIdx.x;
    if (g < n) out[g] += bsums[blockIdx.x];
}

__global__ void copy_kernel(const int* __restrict__ in, int* __restrict__ out, int n) {
    int i = blockIdx.x * blockDim.x + threadIdx.x;
    if (i < n) out[i] = in[i];
}

// pass 1: bin edges by dst bucket, packed (d_local<<17 | s); streaming loops 4x unrolled
__global__ __launch_bounds__(256)
void partition_kernel(const int* __restrict__ src, const int* __restrict__ dst, int E,
                      int* __restrict__ bcur, unsigned* __restrict__ pbuf) {
    __shared__ int hist[NBK];
    __shared__ int runbase[NBK];
    __shared__ int c2[NBK];
    const int tid = threadIdx.x;
    const int e0 = blockIdx.x * CHUNK;
    const int e1 = min(e0 + CHUNK, E);
    for (int t = tid; t < NBK; t += 256) { hist[t] = 0; c2[t] = 0; }
    __syncthreads();
    int i = e0 + tid;
    for (; i + 768 < e1; i += 1024) {
        int d0 = dst[i], d1 = dst[i + 256], d2 = dst[i + 512], d3 = dst[i + 768];
        atomicAdd(&hist[((unsigned)d0) / BKT], 1);
        atomicAdd(&hist[((unsigned)d1) / BKT], 1);
        atomicAdd(&hist[((unsigned)d2) / BKT], 1);
        atomicAdd(&hist[((unsigned)d3) / BKT], 1);
    }
    for (; i < e1; i += 256)
        atomicAdd(&hist[((unsigned)dst[i]) / BKT], 1);
    __syncthreads();
    for (int t = tid; t < NBK; t += 256) {
        int h = hist[t];
        runbase[t] = h ? atomicAdd(&bcur[t], h) : 0;
    }
    __syncthreads();
    i = e0 + tid;
    for (; i + 768 < e1; i += 1024) {
        int d0 = dst[i], d1 = dst[i + 256], d2 = dst[i + 512], d3 = dst[i + 768];
        int s0 = src[i], s1 = src[i + 256], s2 = src[i + 512], s3 = src[i + 768];
        { int b = ((unsigned)d0) / BKT; int ofs = atomicAdd(&c2[b], 1);
          pbuf[runbase[b] + ofs] = (((unsigned)(d0 & (BKT - 1))) << 17) | (unsigned)s0; }
        { int b = ((unsigned)d1) / BKT; int ofs = atomicAdd(&c2[b], 1);
          pbuf[runbase[b] + ofs] = (((unsigned)(d1 & (BKT - 1))) << 17) | (unsigned)s1; }
        { int b = ((unsigned)d2) / BKT; int ofs = atomicAdd(&c2[b], 1);
          pbuf[runbase[b] + ofs] = (((unsigned)(d2 & (BKT - 1))) << 17) | (unsigned)s2; }
        { int b = ((unsigned)d3) / BKT; int ofs = atomicAdd(&c2[b], 1);
          pbuf[runbase[b] + ofs] = (((unsigned)(d3 & (BKT - 1))) << 17) | (unsigned)s3; }
    }
    for (; i < e1; i += 256) {
        int d = dst[i], s = src[i];
        int b = ((unsigned)d) / BKT;
        int ofs = atomicAdd(&c2[b], 1);
        pbuf[runbase[b] + ofs] = (((unsigned)(d & (BKT - 1))) << 17) | (unsigned)s;
    }
}

// pass 2: one block per bucket; streaming loops 4x unrolled
__global__ __launch_bounds__(256)
void bucket_scatter_kernel(const int* __restrict__ bktbase, const unsigned* __restrict__ pbuf,
                           int E, int* __restrict__ ptr, int* __restrict__ ssrc) {
    __shared__ int lcnt[BKT];
    __shared__ int cur[BKT];
    __shared__ int wsum[4];
    const int b = blockIdx.x;
    const int tid = threadIdx.x;
    const int n0 = b * BKT;
    const int nodes = min(BKT, NN - n0);
    const int bstart = bktbase[b];
    const int bend = (b == NBK - 1) ? E : bktbase[b + 1];
    if (tid < BKT) lcnt[tid] = 0;
    __syncthreads();
    int i = bstart + tid;
    for (; i + 768 < bend; i += 1024) {
        unsigned u0 = pbuf[i], u1 = pbuf[i + 256], u2 = pbuf[i + 512], u3 = pbuf[i + 768];
        atomicAdd(&lcnt[u0 >> 17], 1);
        atomicAdd(&lcnt[u1 >> 17], 1);
        atomicAdd(&lcnt[u2 >> 17], 1);
        atomicAdd(&lcnt[u3 >> 17], 1);
    }
    for (; i < bend; i += 256)
        atomicAdd(&lcnt[pbuf[i] >> 17], 1);
    __syncthreads();
    int v = (tid < nodes) ? (lcnt[tid] + 1) : 0;
    int lane = tid & 63, w = tid >> 6;
    int x = v;
    #pragma unroll
    for (int o = 1; o < 64; o <<= 1) {
        int y = __shfl_up(x, o, 64);
        if (lane >= o) x += y;
    }
    if (lane == 63) wsum[w] = x;
    __syncthreads();
    if (tid == 0) {
        int a = 0;
        #pragma unroll
        for (int k = 0; k < 4; ++k) { int t2 = wsum[k]; wsum[k] = a; a += t2; }
    }
    __syncthreads();
    int ex = x - v + wsum[w];
    if (tid < nodes) {
        int p = bstart + n0 + ex;
        ptr[n0 + tid] = p;
        ssrc[p] = n0 + tid;             // self loop at slot 0
        cur[tid] = p + 1;
    }
    __syncthreads();
    i = bstart + tid;
    for (; i + 768 < bend; i += 1024) {
        unsigned u0 = pbuf[i], u1 = pbuf[i + 256], u2 = pbuf[i + 512], u3 = pbuf[i + 768];
        { int pos = atomicAdd(&cur[u0 >> 17], 1); ssrc[pos] = (int)(u0 & 0x1FFFFu); }
        { int pos = atomicAdd(&cur[u1 >> 17], 1); ssrc[pos] = (int)(u1 & 0x1FFFFu); }
        { int pos = atomicAdd(&cur[u2 >> 17], 1); ssrc[pos] = (int)(u2 & 0x1FFFFu); }
        { int pos = atomicAdd(&cur[u3 >> 17], 1); ssrc[pos] = (int)(u3 & 0x1FFFFu); }
    }
    for (; i < bend; i += 256) {
        unsigned u = pbuf[i];
        int pos = atomicAdd(&cur[u >> 17], 1);
        ssrc[pos] = (int)(u & 0x1FFFFu);
    }
}

// ---------------- tier-2 helpers ----------------
__global__ void init_one_kernel(int* __restrict__ cnt, int n) {
    int i = blockIdx.x * blockDim.x + threadIdx.x;
    if (i < n) cnt[i] = 1;
}
__global__ void hist_kernel(const int* __restrict__ dst, int E, int* __restrict__ cnt) {
    int i = blockIdx.x * blockDim.x + threadIdx.x;
    if (i < E) atomicAdd(&cnt[dst[i]], 1);
}
__global__ void scatter_kernel(const int* __restrict__ src, const int* __restrict__ dst,
                               int E, int ET, int* __restrict__ cfill, int* __restrict__ ssrc) {
    int i = blockIdx.x * blockDim.x + threadIdx.x;
    if (i >= ET) return;
    int s, d;
    if (i < E) { s = src[i]; d = dst[i]; }
    else       { s = d = i - E; }
    int pos = atomicAdd(&cfill[d], 1);
    ssrc[pos] = s;
}

// ---------------- fused per-node GAT aggregation + projection (single-pass CSR gather) -----
// one 64-lane wave per node; eighth o handles edges k === o (mod 8), lane t holds
// features 4t..4t+3. Single traversal + cross-iteration ssrc prefetch (r15).
// Epilogue: hbuf LDS + single barrier + full-wave 32x32 projection (r15 version —
// r16's shuffle epilogue regressed: dynamic-srcLane shuffles cost more than the
// barrier-amortized LDS round trip).
//   MODE 0 (MID):  outh = v@W2 (fp16); att dots -> oasrc/oadst
//   MODE 1 (LAST): outf = v@Wr + br (fp32 readout)
template <int MODE>
__global__ __launch_bounds__(256)
void gat_csr_kernel(const int* __restrict__ ptr, const int* __restrict__ ssrc,
                    const float* __restrict__ asrc, const float* __restrict__ adst,
                    const __half* __restrict__ H, const float* __restrict__ bias,
                    const float* __restrict__ Wp, const float* __restrict__ bp,
                    const float* __restrict__ att_s, const float* __restrict__ att_d,
                    __half* __restrict__ outh, float* __restrict__ outf,
                    float* __restrict__ oasrc, float* __restrict__ oadst, int ET) {
    __shared__ float Wl[32 * 32];
    __shared__ float hbuf[4][FOUT];
    const int tid = threadIdx.x;
    for (int i = tid; i < 1024; i += 256) Wl[i] = Wp[i];
    const int w = tid >> 6, lane = tid & 63;
    const int wid = blockIdx.x * 4 + w;
    const int beg = ptr[wid];
    const int end = (wid == NN - 1) ? ET : ptr[wid + 1];
    const int deg = end - beg;
    const int dm1 = deg - 1;
    const float ad = adst[wid];
    const int o = lane >> 3, t = lane & 7;

    float4 a0 = make_float4(0.f, 0.f, 0.f, 0.f);
    float4 a1 = make_float4(0.f, 0.f, 0.f, 0.f);
    float4 a2 = make_float4(0.f, 0.f, 0.f, 0.f);
    float4 a3 = make_float4(0.f, 0.f, 0.f, 0.f);
    float sm0 = 0.f, sm1 = 0.f;
    int k = o;
    int cs0 = ssrc[beg + min(k,      dm1)];
    int cs1 = ssrc[beg + min(k + 8,  dm1)];
    int cs2 = ssrc[beg + min(k + 16, dm1)];
    int cs3 = ssrc[beg + min(k + 24, dm1)];
    while (k < deg) {
        const int nk = k + 32;
        int ns0 = ssrc[beg + min(nk,      dm1)];
        int ns1 = ssrc[beg + min(nk + 8,  dm1)];
        int ns2 = ssrc[beg + min(nk + 16, dm1)];
        int ns3 = ssrc[beg + min(nk + 24, dm1)];
        float e0 = asrc[cs0], e1 = asrc[cs1], e2 = asrc[cs2], e3 = asrc[cs3];
        float4 h0 = ldH4(H, (size_t)cs0 * FOUT + 4 * t);
        float4 h1 = ldH4(H, (size_t)cs1 * FOUT + 4 * t);
        float4 h2 = ldH4(H, (size_t)cs2 * FOUT + 4 * t);
        float4 h3 = ldH4(H, (size_t)cs3 * FOUT + 4 * t);
        float p0 = __expf(lrelu(e0 + ad));
        float p1 = (k + 8  < deg) ? __expf(lrelu(e1 + ad)) : 0.f;
        float p2 = (k + 16 < deg) ? __expf(lrelu(e2 + ad)) : 0.f;
        float p3 = (k + 24 < deg) ? __expf(lrelu(e3 + ad)) : 0.f;
        sm0 += p0 + p2; sm1 += p1 + p3;
        a0.x = fmaf(p0, h0.x, a0.x); a0.y = fmaf(p0, h0.y, a0.y);
        a0.z = fmaf(p0, h0.z, a0.z); a0.w = fmaf(p0, h0.w, a0.w);
        a1.x = fmaf(p1, h1.x, a1.x); a1.y = fmaf(p1, h1.y, a1.y);
        a1.z = fmaf(p1, h1.z, a1.z); a1.w = fmaf(p1, h1.w, a1.w);
        a2.x = fmaf(p2, h2.x, a2.x); a2.y = fmaf(p2, h2.y, a2.y);
        a2.z = fmaf(p2, h2.z, a2.z); a2.w = fmaf(p2, h2.w, a2.w);
        a3.x = fmaf(p3, h3.x, a3.x); a3.y = fmaf(p3, h3.y, a3.y);
        a3.z = fmaf(p3, h3.z, a3.z); a3.w = fmaf(p3, h3.w, a3.w);
        k = nk;
        cs0 = ns0; cs1 = ns1; cs2 = ns2; cs3 = ns3;
    }
    float4 a = make_float4(a0.x + a1.x + a2.x + a3.x, a0.y + a1.y + a2.y + a3.y,
                           a0.z + a1.z + a2.z + a3.z, a0.w + a1.w + a2.w + a3.w);
    float sm = sm0 + sm1;
    #pragma unroll
    for (int off = 8; off <= 32; off <<= 1) {
        a.x += __shfl_xor(a.x, off, 64);
        a.y += __shfl_xor(a.y, off, 64);
        a.z += __shfl_xor(a.z, off, 64);
        a.w += __shfl_xor(a.w, off, 64);
        sm  += __shfl_xor(sm,  off, 64);
    }
    const float inv = 1.f / (sm + 1e-16f);

    // v = relu(agg*inv + bias) -> hbuf (8 lanes), then full-wave projection
    if (lane < 8) {
        float4 bv = *(const float4*)(bias + 4 * t);
        hbuf[w][4 * t]     = fmaxf(fmaf(a.x, inv, bv.x), 0.f);
        hbuf[w][4 * t + 1] = fmaxf(fmaf(a.y, inv, bv.y), 0.f);
        hbuf[w][4 * t + 2] = fmaxf(fmaf(a.z, inv, bv.z), 0.f);
        hbuf[w][4 * t + 3] = fmaxf(fmaf(a.w, inv, bv.w), 0.f);
    }
    __syncthreads();                 // Wl + hbuf visible (uniform barrier)
    {
        const int j = lane & 31, hh = lane >> 5;
        float r = 0.f;
        #pragma unroll
        for (int kk = 0; kk < 16; ++kk) {
            int k2 = hh * 16 + kk;
            r = fmaf(hbuf[w][k2], Wl[k2 * 32 + j], r);
        }
        r += __shfl_xor(r, 32, 64);
        if (MODE == 1) {
            if (lane < 32) outf[(size_t)wid * FOUT + j] = r + bp[j];
        } else {
            float rn = __shfl_xor(r, 1, 64);
            if (lane < 32 && !(j & 1)) {
                __half2 h2 = __float22half2_rn(make_float2(r, rn));
                *(__half2*)(outh + (size_t)wid * FOUT + j) = h2;
            }
            float vs = r * att_s[j];
            float vd = r * att_d[j];
            #pragma unroll
            for (int off = 1; off < 32; off <<= 1) {
                vs += __shfl_xor(vs, off, 64);
                vd += __shfl_xor(vd, off, 64);
            }
            if (lane == 0) { oasrc[wid] = vs; oadst[wid] = vd; }
        }
    }
}

// ---------------- tier-3 fallback (round-2 proven atomic path, all fp32) ----------------
__device__ __forceinline__ unsigned ordf(float f) {
    unsigned u = __float_as_uint(f);
    return (u & 0x80000000u) ? ~u : (u | 0x80000000u);
}
__device__ __forceinline__ float unordf(unsigned u) {
    return (u & 0x80000000u) ? __uint_as_float(u & 0x7FFFFFFFu) : __uint_as_float(~u);
}
__device__ __forceinline__ void edge_sd(int i, int E, const int* __restrict__ src,
                                        const int* __restrict__ dst, int& s, int& d) {
    if (i < E) { s = src[i]; d = dst[i]; }
    else       { s = d = i - E; }
}
__global__ void edge_max_kernel(const int* __restrict__ src, const int* __restrict__ dst,
                                const float* __restrict__ a_src, const float* __restrict__ a_dst,
                                unsigned* __restrict__ m, int E, int ET) {
    int i = blockIdx.x * blockDim.x + threadIdx.x;
    if (i >= ET) return;
    int s, d; edge_sd(i, E, src, dst, s, d);
    atomicMax(m + d, ordf(lrelu(a_src[s] + a_dst[d])));
}
__global__ void edge_denom_kernel(const int* __restrict__ src, const int* __restrict__ dst,
                                  const float* __restrict__ a_src, const float* __restrict__ a_dst,
                                  const unsigned* __restrict__ m, float* __restrict__ denom,
                                  int E, int ET) {
    int i = blockIdx.x * blockDim.x + threadIdx.x;
    if (i >= ET) return;
    int s, d; edge_sd(i, E, src, dst, s, d);
    atomicAdd(denom + d, __expf(lrelu(a_src[s] + a_dst[d]) - unordf(m[d])));
}
__global__ void edge_accum_kernel(const int* __restrict__ src, const int* __restrict__ dst,
                                  const float* __restrict__ a_src, const float* __restrict__ a_dst,
                                  const unsigned* __restrict__ m, const float* __restrict__ denom,
                                  const float* __restrict__ H, float* __restrict__ accum,
                                  int E, int ET) {
    long tid = (long)blockIdx.x * blockDim.x + threadIdx.x;
    if (tid >= (long)ET * FOUT) return;
    int i = (int)(tid >> 5);
    int j = (int)(tid & 31);
    int s, d; edge_sd(i, E, src, dst, s, d);
    float w = __expf(lrelu(a_src[s] + a_dst[d]) - unordf(m[d])) / (denom[d] + 1e-16f);
    atomicAdd(accum + (long)d * FOUT + j, w * H[(long)s * FOUT + j]);
}
__global__ void finalize_kernel(float* __restrict__ accum, const float* __restrict__ bias, int N) {
    int tid = blockIdx.x * blockDim.x + threadIdx.x;
    if (tid >= N * FOUT) return;
    int j = tid & 31;
    accum[tid] = fmaxf(accum[tid] + bias[j], 0.f);
}

extern "C" void kernel_launch(void* const* d_in, const int* in_sizes, int n_in,
                              void* d_out, int out_size, void* d_ws, size_t ws_size,
                              hipStream_t stream) {
    const float* x   = (const float*)d_in[0];
    const int*   ei  = (const int*)d_in[1];
    const float* W1  = (const float*)d_in[2];
    const float* as1 = (const float*)d_in[3];
    const float* ad1 = (const float*)d_in[4];
    const float* b1  = (const float*)d_in[5];
    const float* W2  = (const float*)d_in[6];
    const float* as2 = (const float*)d_in[7];
    const float* ad2 = (const float*)d_in[8];
    const float* b2  = (const float*)d_in[9];
    const float* Wr  = (const float*)d_in[10];
    const float* br  = (const float*)d_in[11];
    float* out = (float*)d_out;

    const int E  = in_sizes[1] / 2;
    const int*  src = ei;
    const int*  dst = ei + E;
    const int ET = E + NN;

    const size_t NF = (size_t)NN * FOUT;
    // layout (float units): A(NF) | H(NF) | asrc(NN) | adst(NN) | asrc2(NN) | adst2(NN)
    //                       | ptr(NN) | cnt(NN) | bsum(512) | ssrc(ET)
    float* A     = (float*)d_ws;
    float* H     = A + NF;
    float* asrc  = H + NF;
    float* adst  = asrc + NN;
    float* asrc2 = adst + NN;
    float* adst2 = asrc2 + NN;
    int*   ptr   = (int*)(adst2 + NN);
    int*   cnt   = ptr + NN;
    int*   bsum  = cnt + NN;
    int*   ssrc  = bsum + 512;
    __half* H1h  = (__half*)H;
    __half* H2h  = (__half*)A;
    const size_t need = (2 * NF + 6 * (size_t)NN + 512 + (size_t)ET) * 4;

    dim3 blk(256);
    const int nb  = (NN + 7) / 8;
    const int fb  = (NN * FOUT + 255) / 256;
    const int nb1 = (NN + 255) / 256;   // 391

    if (ws_size >= need && (size_t)E <= NF) {
        // ================= tier 1 =================
        unsigned* pbuf    = (unsigned*)A;
        int*      bktcnt  = cnt;
        int*      bktbase = cnt + 1024;
        int*      bcur    = cnt + 2048;
        const int cb = (E + CHUNK - 1) / CHUNK;   // 391 with CHUNK=8192
        const int gb = NN / 4;

        hipMemsetAsync(bktcnt, 0, NBK * sizeof(int), stream);
        count_tr1_kernel<<<cb + nb, blk, 0, stream>>>(dst, E, cb, bktcnt,
                                                      x, W1, as1, ad1, H1h,
                                                      asrc, adst, NN, 128);
        scan_blocks_kernel<1024><<<1, 1024, 0, stream>>>(bktcnt, NBK, bktbase, bcur, nullptr);
        partition_kernel<<<cb, blk, 0, stream>>>(src, dst, E, bcur, pbuf);
        bucket_scatter_kernel<<<NBK, blk, 0, stream>>>(bktbase, pbuf, E, ptr, ssrc);

        gat_csr_kernel<0><<<gb, blk, 0, stream>>>(ptr, ssrc, asrc, adst, H1h, b1,
                                                  W2, nullptr, as2, ad2,
                                                  H2h, nullptr, asrc2, adst2, ET);
        gat_csr_kernel<1><<<gb, blk, 0, stream>>>(ptr, ssrc, asrc2, adst2, H2h, b2,
                                                  Wr, br, nullptr, nullptr,
                                                  nullptr, out, nullptr, nullptr, ET);
    } else if (ws_size >= need) {
        // ================= tier 2: per-node hist + simple scatter =================
        const int gb = NN / 4;
        init_one_kernel<<<nb1, blk, 0, stream>>>(cnt, NN);
        hist_kernel<<<(E + 255) / 256, blk, 0, stream>>>(dst, E, cnt);
        scan_blocks_kernel<256><<<nb1, blk, 0, stream>>>(cnt, NN, ptr, nullptr, bsum);
        scan_blocks_kernel<512><<<1, 512, 0, stream>>>(bsum, nb1, bsum, nullptr, nullptr);
        add_offsets_kernel<<<nb1, blk, 0, stream>>>(ptr, bsum, NN);
        copy_kernel<<<nb1, blk, 0, stream>>>(ptr, cnt, NN);
        scatter_kernel<<<(ET + 255) / 256, blk, 0, stream>>>(src, dst, E, ET, cnt, ssrc);

        transform_kernel<true, false, __half><<<nb, blk, 0, stream>>>(
            x, W1, as1, ad1, nullptr, H1h, asrc, adst, NN, 128);
        gat_csr_kernel<0><<<gb, blk, 0, stream>>>(ptr, ssrc, asrc, adst, H1h, b1,
                                                  W2, nullptr, as2, ad2,
                                                  H2h, nullptr, asrc2, adst2, ET);
        gat_csr_kernel<1><<<gb, blk, 0, stream>>>(ptr, ssrc, asrc2, adst2, H2h, b2,
                                                  Wr, br, nullptr, nullptr,
                                                  nullptr, out, nullptr, nullptr, ET);
    } else {
        // ================= tier 3: atomic path (all fp32) =================
        unsigned* m   = (unsigned*)ptr;
        float*    den = (float*)cnt;
        const int eb = (ET + 255) / 256;
        const int ab = (int)(((long)ET * FOUT + 255) / 256);

        hipMemsetAsync(A, 0, NF * sizeof(float), stream);
        hipMemsetAsync(m, 0, NN * sizeof(int), stream);
        hipMemsetAsync(den, 0, NN * sizeof(float), stream);
        transform_kernel<true, false, float><<<nb, blk, 0, stream>>>(
            x, W1, as1, ad1, nullptr, H, asrc, adst, NN, 128);
        edge_max_kernel<<<eb, blk, 0, stream>>>(src, dst, asrc, adst, m, E, ET);
        edge_denom_kernel<<<eb, blk, 0, stream>>>(src, dst, asrc, adst, m, den, E, ET);
        edge_accum_kernel<<<ab, blk, 0, stream>>>(src, dst, asrc, adst, m, den, H, A, E, ET);
        finalize_kernel<<<fb, blk, 0, stream>>>(A, b1, NN);

        transform_kernel<true, false, float><<<nb, blk, 0, stream>>>(
            A, W2, as2, ad2, nullptr, H, asrc, adst, NN, 32);
        hipMemsetAsync(A, 0, NF * sizeof(float), stream);
        hipMemsetAsync(m, 0, NN * sizeof(int), stream);
        hipMemsetAsync(den, 0, NN * sizeof(float), stream);
        edge_max_kernel<<<eb, blk, 0, stream>>>(src, dst, asrc, adst, m, E, ET);
        edge_denom_kernel<<<eb, blk, 0, stream>>>(src, dst, asrc, adst, m, den, E, ET);
        edge_accum_kernel<<<ab, blk, 0, stream>>>(src, dst, asrc, adst, m, den, H, A, E, ET);
        finalize_kernel<<<fb, blk, 0, stream>>>(A, b2, NN);

        transform_kernel<false, true, float><<<nb, blk, 0, stream>>>(
            A, Wr, nullptr, nullptr, br, out, nullptr, nullptr, NN, 32);
    }
}